// Round 4
// baseline (440.169 us; speedup 1.0000x reference)
//
#include <hip/hip_runtime.h>
#include <math.h>

#define BB  4
#define SS  1024
#define DD  512
#define HH  8
#define DHD 64
#define PL  2097152      // elements per Q/K/V/Ob plane
#define WPL 262144       // elements per W plane

constexpr float LN_EPS = 1e-5f;

using short8 = __attribute__((ext_vector_type(8))) short;
using f32x4  = __attribute__((ext_vector_type(4))) float;

__device__ __forceinline__ unsigned short f2bf(float f) {
    unsigned int u = __float_as_uint(f);
    u += 0x7FFFu + ((u >> 16) & 1u);     // RNE
    return (unsigned short)(u >> 16);
}
__device__ __forceinline__ float bf2f(unsigned short s) {
    return __uint_as_float((unsigned int)s << 16);
}
__device__ __forceinline__ short8 negbf(short8 a) {
    union { short8 s; unsigned int u[4]; } t;
    t.s = a;
    #pragma unroll
    for (int i = 0; i < 4; ++i) t.u[i] ^= 0x80008000u;
    return t.s;
}
// swizzled fragment loads: 64-wide rows and 32-wide rows
__device__ __forceinline__ short8 ld64(const unsigned short* p, int row, int col) {
    return *(const short8*)(p + row * 64 + (col ^ ((row & 7) << 3)));
}
__device__ __forceinline__ short8 ld32(const unsigned short* p, int row, int col) {
    return *(const short8*)(p + row * 32 + (col ^ ((row & 3) << 3)));
}
#define MFMA(acc, a, b) acc = __builtin_amdgcn_mfma_f32_16x16x32_bf16(a, b, acc, 0, 0, 0)

// ---------------------------------------------------------------------------
// Kernel 0: split Wq/Wk/Wv (fp32 complex [512][512]) into hi/lo r/i bf16 planes.
// Plane order per matrix: [rhi, rlo, ihi, ilo].
// ---------------------------------------------------------------------------
__global__ __launch_bounds__(256)
void wsplit_kernel(const float2* __restrict__ Wq, const float2* __restrict__ Wk,
                   const float2* __restrict__ Wv, unsigned short* __restrict__ WP) {
    const int mat = blockIdx.y;
    const float2* W = mat == 0 ? Wq : (mat == 1 ? Wk : Wv);
    unsigned short* base = WP + (size_t)mat * 4 * WPL;
    const int idx = (blockIdx.x * 256 + threadIdx.x) * 2;   // complex index, 2/thread
    float4 t = *(const float4*)(W + idx);
    unsigned short rh0 = f2bf(t.x), ih0 = f2bf(t.y);
    unsigned short rh1 = f2bf(t.z), ih1 = f2bf(t.w);
    unsigned short rl0 = f2bf(t.x - bf2f(rh0)), il0 = f2bf(t.y - bf2f(ih0));
    unsigned short rl1 = f2bf(t.z - bf2f(rh1)), il1 = f2bf(t.w - bf2f(ih1));
    const int ui = idx >> 1;
    ((unsigned int*)(base + 0 * WPL))[ui] = (unsigned int)rh0 | ((unsigned int)rh1 << 16);
    ((unsigned int*)(base + 1 * WPL))[ui] = (unsigned int)rl0 | ((unsigned int)rl1 << 16);
    ((unsigned int*)(base + 2 * WPL))[ui] = (unsigned int)ih0 | ((unsigned int)ih1 << 16);
    ((unsigned int*)(base + 3 * WPL))[ui] = (unsigned int)il0 | ((unsigned int)il1 << 16);
}

// ---------------------------------------------------------------------------
// Kernel 1: complex projection, split-bf16 MFMA (3-term per real product).
// K-chunk 32 -> 32 KB LDS -> 5 blocks/CU (occupancy was the round-3 limiter).
// Q/K out: hi/lo r/i planes [BH][S][64]; V out: pre-transposed [BH][64][S].
// ---------------------------------------------------------------------------
__global__ __launch_bounds__(256, 5)
void proj_kernel(const float2* __restrict__ qin, const float2* __restrict__ kin,
                 const float2* __restrict__ vin,
                 const unsigned short* __restrict__ WP,
                 const float2* __restrict__ bq, const float2* __restrict__ bk,
                 const float2* __restrict__ bv,
                 unsigned short* __restrict__ QG, unsigned short* __restrict__ KG,
                 unsigned short* __restrict__ VG) {
    const float2* X; const float2* bias; unsigned short* outP;
    const unsigned short* WM = WP + (size_t)blockIdx.z * 4 * WPL;
    if (blockIdx.z == 0)      { X = qin; bias = bq; outP = QG; }
    else if (blockIdx.z == 1) { X = kin; bias = bk; outP = KG; }
    else                      { X = vin; bias = bv; outP = VG; }
    const bool isV = (blockIdx.z == 2);

    __shared__ unsigned short Xs[4][2048];   // [rhi,rlo,ihi,ilo][64 m][32 d]
    __shared__ unsigned short Ws[4][2048];   // [rhi,rlo,ihi,ilo][64 e][32 d]

    const int tid  = threadIdx.x;
    const int w    = tid >> 6;
    const int lane = tid & 63;
    const int quad = lane >> 4;
    const int l15  = lane & 15;
    const int m0   = blockIdx.x * 64;
    const int h    = blockIdx.y;
    const int e0   = h * 64;

    const int srow = tid >> 2;          // 0..63
    const int sseg = (tid & 3) * 8;     // 0,8,16,24
    const int soff = srow * 32 + (sseg ^ ((srow & 3) << 3));

    f32x4 Sr[4], Si[4];
    #pragma unroll
    for (int i = 0; i < 4; ++i) { Sr[i] = (f32x4)0.f; Si[i] = (f32x4)0.f; }

    for (int dc = 0; dc < DD; dc += 32) {
        if (dc) __syncthreads();
        // --- X chunk: fp32 complex -> hi/lo r/i bf16 (8 complex / thread) ---
        {
            const float4* xp = (const float4*)(X + (size_t)(m0 + srow) * DD + dc + sseg);
            union { unsigned short u[8]; uint4 q; } rh, rl, ih, il;
            #pragma unroll
            for (int j = 0; j < 4; ++j) {
                float4 t = xp[j];
                int a = 2 * j, b2 = 2 * j + 1;
                rh.u[a]  = f2bf(t.x); rl.u[a]  = f2bf(t.x - bf2f(rh.u[a]));
                ih.u[a]  = f2bf(t.y); il.u[a]  = f2bf(t.y - bf2f(ih.u[a]));
                rh.u[b2] = f2bf(t.z); rl.u[b2] = f2bf(t.z - bf2f(rh.u[b2]));
                ih.u[b2] = f2bf(t.w); il.u[b2] = f2bf(t.w - bf2f(ih.u[b2]));
            }
            *(uint4*)&Xs[0][soff] = rh.q;
            *(uint4*)&Xs[1][soff] = rl.q;
            *(uint4*)&Xs[2][soff] = ih.q;
            *(uint4*)&Xs[3][soff] = il.q;
        }
        // --- W chunk: direct bf16 plane copies ---
        {
            const size_t wo = (size_t)(e0 + srow) * DD + dc + sseg;
            #pragma unroll
            for (int p = 0; p < 4; ++p)
                *(uint4*)&Ws[p][soff] = *(const uint4*)(WM + (size_t)p * WPL + wo);
        }
        __syncthreads();

        const int mrow = w * 16 + l15;
        const int dl   = quad * 8;
        short8 xrh = ld32(Xs[0], mrow, dl);
        short8 xrl = ld32(Xs[1], mrow, dl);
        short8 xih = ld32(Xs[2], mrow, dl);
        short8 xil = ld32(Xs[3], mrow, dl);
        short8 xmih = negbf(xih), xmil = negbf(xil);
        #pragma unroll
        for (int et = 0; et < 4; ++et) {
            const int er = et * 16 + l15;
            short8 wrh = ld32(Ws[0], er, dl);
            short8 wrl = ld32(Ws[1], er, dl);
            short8 wih = ld32(Ws[2], er, dl);
            short8 wil = ld32(Ws[3], er, dl);
            // Sr = XrWr - XiWi (3-term splits)
            MFMA(Sr[et], xrh,  wrh); MFMA(Sr[et], xrh,  wrl); MFMA(Sr[et], xrl,  wrh);
            MFMA(Sr[et], xmih, wih); MFMA(Sr[et], xmih, wil); MFMA(Sr[et], xmil, wih);
            // Si = XrWi + XiWr
            MFMA(Si[et], xrh,  wih); MFMA(Si[et], xrh,  wil); MFMA(Si[et], xrl,  wih);
            MFMA(Si[et], xih,  wrh); MFMA(Si[et], xih,  wrl); MFMA(Si[et], xil,  wrh);
        }
    }

    // epilogue: + bias, hi/lo split, write planes (V transposed)
    #pragma unroll
    for (int et = 0; et < 4; ++et) {
        const int col = et * 16 + l15;
        float2 bb = bias[e0 + col];
        #pragma unroll
        for (int reg = 0; reg < 4; ++reg) {
            int m = m0 + w * 16 + quad * 4 + reg;
            int b = m >> 10;
            int s = m & 1023;
            int bh = b * HH + h;
            float vr = Sr[et][reg] + bb.x;
            float vi = Si[et][reg] + bb.y;
            unsigned short rh = f2bf(vr), ih2 = f2bf(vi);
            unsigned short rl = f2bf(vr - bf2f(rh)), il2 = f2bf(vi - bf2f(ih2));
            size_t o = isV ? ((size_t)bh * DHD + col) * SS + s
                           : ((size_t)bh * SS + s) * DHD + col;
            outP[0 * PL + o] = rh;
            outP[1 * PL + o] = rl;
            outP[2 * PL + o] = ih2;
            outP[3 * PL + o] = il2;
        }
    }
}

// ---------------------------------------------------------------------------
// Kernel 2: MFMA flash attention, split-bf16 scores, dual fixed-max softmax.
// 512 threads (8 waves). k-tile 64/iter, wave-halves split the k range
// (softmax has no running max -> partials are additive; combined via LDS at
// the end). 16 waves/CU (2 blocks x 80 KB LDS). Output: bf16 r/i planes.
// ---------------------------------------------------------------------------
__global__ __launch_bounds__(512, 4)
void attn_kernel(const unsigned short* __restrict__ QG, const unsigned short* __restrict__ KG,
                 const unsigned short* __restrict__ VG,
                 unsigned short* __restrict__ ObR, unsigned short* __restrict__ ObI) {
    __shared__ __align__(16) unsigned char smem[81920];
    unsigned short* Ks = (unsigned short*)smem;            // 4 planes x [64 k][64 d]
    unsigned short* Vt = (unsigned short*)(smem + 32768);  // 4 planes x [64 d][64 k]
    unsigned short* Ps = (unsigned short*)(smem + 65536);  // [r,i][8 waves][16 q][32 k]
    f32x4* comb = (f32x4*)smem;                            // end-of-kernel combine scratch

    const int tid  = threadIdx.x;
    const int w    = tid >> 6;
    const int lane = tid & 63;
    const int quad = lane >> 4;
    const int l15  = lane & 15;
    const int qg   = w & 3;            // q-group (16 rows)
    const int h32  = (w >> 2) * 32;    // wave's k-half within the 64-k tile
    const int q0   = blockIdx.x * 64;
    const int bh   = blockIdx.y;
    const int b    = bh >> 3;
    const int h    = bh & 7;

    // Q fragments (hi/lo r/i) once from global, held in registers
    short8 qrh[2], qrl[2], qih[2], qil[2];
    #pragma unroll
    for (int kc = 0; kc < 2; ++kc) {
        size_t qb = ((size_t)bh * SS + q0 + qg * 16 + l15) * DHD + kc * 32 + quad * 8;
        qrh[kc] = *(const short8*)(QG + 0 * PL + qb);
        qrl[kc] = *(const short8*)(QG + 1 * PL + qb);
        qih[kc] = *(const short8*)(QG + 2 * PL + qb);
        qil[kc] = *(const short8*)(QG + 3 * PL + qb);
    }

    f32x4 acc[4][4];   // [rr,ri,ir,ii][dt]
    #pragma unroll
    for (int p = 0; p < 4; ++p)
        #pragma unroll
        for (int dt = 0; dt < 4; ++dt) acc[p][dt] = (f32x4)0.f;
    float lrp[4] = {0.f, 0.f, 0.f, 0.f}, lip[4] = {0.f, 0.f, 0.f, 0.f};

    unsigned short* PrW = Ps + w * 512;
    unsigned short* PiW = Ps + 4096 + w * 512;

    const int srow = tid >> 3;          // 0..63 (k row for K, d row for V^T)
    const int sseg = (tid & 7) * 8;
    const int soff = srow * 64 + (sseg ^ ((srow & 7) << 3));

    for (int kt = 0; kt < SS; kt += 64) {
        if (kt) __syncthreads();
        // ---- stage K [64k][64d] and V^T [64d][64k], split across 8 waves ----
        #pragma unroll
        for (int p = 0; p < 4; ++p) {
            *(uint4*)&Ks[p * 4096 + soff] =
                *(const uint4*)(KG + (size_t)p * PL + ((size_t)bh * SS + kt + srow) * DHD + sseg);
            *(uint4*)&Vt[p * 4096 + soff] =
                *(const uint4*)(VG + (size_t)p * PL + ((size_t)bh * DHD + srow) * SS + kt + sseg);
        }
        __syncthreads();

        // ---- scores: split complex QK^T over this wave's 32-k half ----
        f32x4 Sr[2], Si[2];
        Sr[0] = (f32x4)0.f; Sr[1] = (f32x4)0.f; Si[0] = (f32x4)0.f; Si[1] = (f32x4)0.f;
        #pragma unroll
        for (int kc = 0; kc < 2; ++kc) {
            const int dl = kc * 32 + quad * 8;
            #pragma unroll
            for (int nt = 0; nt < 2; ++nt) {
                const int kr = h32 + nt * 16 + l15;
                short8 krh = ld64(Ks + 0 * 4096, kr, dl);
                short8 krl = ld64(Ks + 1 * 4096, kr, dl);
                short8 kih = ld64(Ks + 2 * 4096, kr, dl);
                short8 kil = ld64(Ks + 3 * 4096, kr, dl);
                short8 kmih = negbf(kih), kmil = negbf(kil);
                // Sr = QrKr - QiKi
                MFMA(Sr[nt], qrh[kc], krh);  MFMA(Sr[nt], qrh[kc], krl);  MFMA(Sr[nt], qrl[kc], krh);
                MFMA(Sr[nt], qih[kc], kmih); MFMA(Sr[nt], qih[kc], kmil); MFMA(Sr[nt], qil[kc], kmih);
                // Si = QrKi + QiKr
                MFMA(Si[nt], qrh[kc], kih);  MFMA(Si[nt], qrh[kc], kil);  MFMA(Si[nt], qrl[kc], kih);
                MFMA(Si[nt], qih[kc], krh);  MFMA(Si[nt], qih[kc], krl);  MFMA(Si[nt], qil[kc], krh);
            }
        }

        // ---- dual softmax numerators (|s/8| < ~6, fixed max): P = exp(s/8) ----
        #pragma unroll
        for (int nt = 0; nt < 2; ++nt) {
            #pragma unroll
            for (int reg = 0; reg < 4; ++reg) {
                float pr = __expf(Sr[nt][reg] * 0.125f);
                float pi = __expf(Si[nt][reg] * 0.125f);
                unsigned short ph = f2bf(pr), pih2 = f2bf(pi);
                lrp[reg] += bf2f(ph);          // l from rounded p: consistent weights
                lip[reg] += bf2f(pih2);
                int qq = quad * 4 + reg;
                int kcol = nt * 16 + l15;
                PrW[qq * 32 + (kcol ^ ((qq & 3) << 3))] = ph;
                PiW[qq * 32 + (kcol ^ ((qq & 3) << 3))] = pih2;
            }
        }
        // wave-private LDS round-trip; compiler inserts lgkmcnt, no barrier

        // ---- PV over this wave's 32-k half: P (bf16) x V (hi/lo) ----
        {
            const int kl = quad * 8;
            short8 prF = ld32(PrW, l15, kl);
            short8 piF = ld32(PiW, l15, kl);
            const int vcol = h32 + kl;
            #pragma unroll
            for (int dt = 0; dt < 4; ++dt) {
                const int d = dt * 16 + l15;
                short8 vrh = ld64(Vt + 0 * 4096, d, vcol);
                short8 vrl = ld64(Vt + 1 * 4096, d, vcol);
                short8 vih = ld64(Vt + 2 * 4096, d, vcol);
                short8 vil = ld64(Vt + 3 * 4096, d, vcol);
                MFMA(acc[0][dt], prF, vrh); MFMA(acc[0][dt], prF, vrl);
                MFMA(acc[1][dt], prF, vih); MFMA(acc[1][dt], prF, vil);
                MFMA(acc[2][dt], piF, vrh); MFMA(acc[2][dt], piF, vrl);
                MFMA(acc[3][dt], piF, vih); MFMA(acc[3][dt], piF, vil);
            }
        }
    }

    // ---- combine wave-halves: waves 4..7 hand their partial (acc, l) to 0..3 ----
    __syncthreads();                     // K/V/P dead; smem becomes combine scratch
    if (w >= 4) {
        const int base = ((w - 4) * 18) * 64 + lane;
        #pragma unroll
        for (int p = 0; p < 4; ++p)
            #pragma unroll
            for (int dt = 0; dt < 4; ++dt)
                comb[base + (p * 4 + dt) * 64] = acc[p][dt];
        f32x4 lv, li2;
        #pragma unroll
        for (int reg = 0; reg < 4; ++reg) { lv[reg] = lrp[reg]; li2[reg] = lip[reg]; }
        comb[base + 16 * 64] = lv;
        comb[base + 17 * 64] = li2;
    }
    __syncthreads();
    if (w < 4) {
        const int base = (w * 18) * 64 + lane;
        #pragma unroll
        for (int p = 0; p < 4; ++p)
            #pragma unroll
            for (int dt = 0; dt < 4; ++dt)
                acc[p][dt] += comb[base + (p * 4 + dt) * 64];
        f32x4 lv = comb[base + 16 * 64];
        f32x4 li2 = comb[base + 17 * 64];
        #pragma unroll
        for (int reg = 0; reg < 4; ++reg) { lrp[reg] += lv[reg]; lip[reg] += li2[reg]; }

        // reduce l across the 16 lanes of each quad, combine, store bf16
        float ir[4], ii[4];
        #pragma unroll
        for (int reg = 0; reg < 4; ++reg) {
            float a = lrp[reg], c = lip[reg];
            #pragma unroll
            for (int mk = 1; mk < 16; mk <<= 1) {
                a += __shfl_xor(a, mk);
                c += __shfl_xor(c, mk);
            }
            ir[reg] = 1.f / a;
            ii[reg] = 1.f / c;
        }
        #pragma unroll
        for (int dt = 0; dt < 4; ++dt) {
            #pragma unroll
            for (int reg = 0; reg < 4; ++reg) {
                int q   = q0 + w * 16 + quad * 4 + reg;
                int col = h * DHD + dt * 16 + l15;
                float outr = acc[0][dt][reg] * ir[reg] - acc[3][dt][reg] * ii[reg];
                float outi = acc[1][dt][reg] * ir[reg] + acc[2][dt][reg] * ii[reg];
                size_t o = ((size_t)b * SS + q) * DD + col;
                ObR[o] = f2bf(outr);
                ObI[o] = f2bf(outi);
            }
        }
    }
}

// ---------------------------------------------------------------------------
// Kernel 3: residual + dual LayerNorm over D (biased var, eps inside sqrt)
// ---------------------------------------------------------------------------
__global__ __launch_bounds__(256)
void ln_kernel(const unsigned short* __restrict__ OrP, const unsigned short* __restrict__ OiP,
               const float2* __restrict__ Qin,
               const float* __restrict__ gr, const float* __restrict__ br,
               const float* __restrict__ gi, const float* __restrict__ bi,
               float2* __restrict__ out) {
    const int row = blockIdx.x;           // b*S + s
    const int tid = threadIdx.x;
    const size_t base = (size_t)row * DD;
    const int e0 = 2 * tid, e1 = 2 * tid + 1;

    unsigned int ar = *(const unsigned int*)(OrP + base + e0);
    unsigned int ai = *(const unsigned int*)(OiP + base + e0);
    float2 r0 = Qin[base + e0];
    float2 r1 = Qin[base + e1];
    float xr0 = __uint_as_float(ar << 16) + r0.x;
    float xr1 = __uint_as_float(ar & 0xFFFF0000u) + r1.x;
    float xi0 = __uint_as_float(ai << 16) + r0.y;
    float xi1 = __uint_as_float(ai & 0xFFFF0000u) + r1.y;

    float sr = xr0 + xr1;
    float si = xi0 + xi1;
    float qr = xr0 * xr0 + xr1 * xr1;
    float qi = xi0 * xi0 + xi1 * xi1;
    #pragma unroll
    for (int off = 32; off > 0; off >>= 1) {
        sr += __shfl_down(sr, off);
        si += __shfl_down(si, off);
        qr += __shfl_down(qr, off);
        qi += __shfl_down(qi, off);
    }
    __shared__ float red[4][4];
    __shared__ float stat[4];
    int lane = tid & 63, wid = tid >> 6;
    if (lane == 0) { red[wid][0] = sr; red[wid][1] = si; red[wid][2] = qr; red[wid][3] = qi; }
    __syncthreads();
    if (tid == 0) {
        sr = red[0][0] + red[1][0] + red[2][0] + red[3][0];
        si = red[0][1] + red[1][1] + red[2][1] + red[3][1];
        qr = red[0][2] + red[1][2] + red[2][2] + red[3][2];
        qi = red[0][3] + red[1][3] + red[2][3] + red[3][3];
        float mur = sr * (1.f / DD), mui = si * (1.f / DD);
        float vr = qr * (1.f / DD) - mur * mur;
        float vi = qi * (1.f / DD) - mui * mui;
        stat[0] = mur; stat[1] = mui;
        stat[2] = rsqrtf(vr + LN_EPS); stat[3] = rsqrtf(vi + LN_EPS);
    }
    __syncthreads();
    float mur = stat[0], mui = stat[1], rsr = stat[2], rsi = stat[3];
    out[base + e0] = make_float2((xr0 - mur) * rsr * gr[e0] + br[e0],
                                 (xi0 - mui) * rsi * gi[e0] + bi[e0]);
    out[base + e1] = make_float2((xr1 - mur) * rsr * gr[e1] + br[e1],
                                 (xi1 - mui) * rsi * gi[e1] + bi[e1]);
}

// ---------------------------------------------------------------------------
extern "C" void kernel_launch(void* const* d_in, const int* in_sizes, int n_in,
                              void* d_out, int out_size, void* d_ws, size_t ws_size,
                              hipStream_t stream) {
    const float2* q  = (const float2*)d_in[0];
    const float2* k  = (const float2*)d_in[1];
    const float2* v  = (const float2*)d_in[2];
    const float2* Wq = (const float2*)d_in[3];
    const float2* bq = (const float2*)d_in[4];
    const float2* Wk = (const float2*)d_in[5];
    const float2* bk = (const float2*)d_in[6];
    const float2* Wv = (const float2*)d_in[7];
    const float2* bv = (const float2*)d_in[8];
    const float*  gr = (const float*)d_in[9];
    const float*  br = (const float*)d_in[10];
    const float*  gi = (const float*)d_in[11];
    const float*  bi = (const float*)d_in[12];

    // workspace layout (bf16 elements): W planes, Q planes, K planes, V planes, Ob
    unsigned short* WP  = (unsigned short*)d_ws;           // 3*4*WPL
    unsigned short* QG  = WP + (size_t)3 * 4 * WPL;        // 4*PL  [BH][S][64]
    unsigned short* KG  = QG + (size_t)4 * PL;             // 4*PL  [BH][S][64]
    unsigned short* VG  = KG + (size_t)4 * PL;             // 4*PL  [BH][64][S] (transposed)
    unsigned short* ObR = VG + (size_t)4 * PL;             // PL    [B*S*D]
    unsigned short* ObI = ObR + (size_t)PL;                // PL

    wsplit_kernel<<<dim3(512, 3), 256, 0, stream>>>(Wq, Wk, Wv, WP);
    proj_kernel<<<dim3(64, 8, 3), 256, 0, stream>>>(q, k, v, WP, bq, bk, bv, QG, KG, VG);
    attn_kernel<<<dim3(SS / 64, BB * HH), 512, 0, stream>>>(QG, KG, VG, ObR, ObI);
    ln_kernel<<<dim3(BB * SS), 256, 0, stream>>>(ObR, ObI, q, gr, br, gi, bi, (float2*)d_out);
}

// Round 5
// 316.147 us; speedup vs baseline: 1.3923x; 1.3923x over previous
//
#include <hip/hip_runtime.h>
#include <math.h>

#define BB  4
#define SS  1024
#define DD  512
#define HH  8
#define DHD 64
#define PL  2097152      // elements per Q/K/V/Ob plane
#define WPL 262144       // elements per W plane

constexpr float LN_EPS = 1e-5f;

using short8 = __attribute__((ext_vector_type(8))) short;
using f32x4  = __attribute__((ext_vector_type(4))) float;

__device__ __forceinline__ unsigned short f2bf(float f) {
    unsigned int u = __float_as_uint(f);
    u += 0x7FFFu + ((u >> 16) & 1u);     // RNE
    return (unsigned short)(u >> 16);
}
__device__ __forceinline__ float bf2f(unsigned short s) {
    return __uint_as_float((unsigned int)s << 16);
}
__device__ __forceinline__ short8 negbf(short8 a) {
    union { short8 s; unsigned int u[4]; } t;
    t.s = a;
    #pragma unroll
    for (int i = 0; i < 4; ++i) t.u[i] ^= 0x80008000u;
    return t.s;
}
// swizzled fragment loads: 64-wide rows and 32-wide rows
__device__ __forceinline__ short8 ld64(const unsigned short* p, int row, int col) {
    return *(const short8*)(p + row * 64 + (col ^ ((row & 7) << 3)));
}
__device__ __forceinline__ short8 ld32(const unsigned short* p, int row, int col) {
    return *(const short8*)(p + row * 32 + (col ^ ((row & 3) << 3)));
}
#define MFMA(acc, a, b) acc = __builtin_amdgcn_mfma_f32_16x16x32_bf16(a, b, acc, 0, 0, 0)

// ---------------------------------------------------------------------------
// Kernel 0: split Wq/Wk/Wv (fp32 complex [512][512]) into hi/lo r/i bf16 planes.
// ---------------------------------------------------------------------------
__global__ __launch_bounds__(256)
void wsplit_kernel(const float2* __restrict__ Wq, const float2* __restrict__ Wk,
                   const float2* __restrict__ Wv, unsigned short* __restrict__ WP) {
    const int mat = blockIdx.y;
    const float2* W = mat == 0 ? Wq : (mat == 1 ? Wk : Wv);
    unsigned short* base = WP + (size_t)mat * 4 * WPL;
    const int idx = (blockIdx.x * 256 + threadIdx.x) * 2;   // complex index, 2/thread
    float4 t = *(const float4*)(W + idx);
    unsigned short rh0 = f2bf(t.x), ih0 = f2bf(t.y);
    unsigned short rh1 = f2bf(t.z), ih1 = f2bf(t.w);
    unsigned short rl0 = f2bf(t.x - bf2f(rh0)), il0 = f2bf(t.y - bf2f(ih0));
    unsigned short rl1 = f2bf(t.z - bf2f(rh1)), il1 = f2bf(t.w - bf2f(ih1));
    const int ui = idx >> 1;
    ((unsigned int*)(base + 0 * WPL))[ui] = (unsigned int)rh0 | ((unsigned int)rh1 << 16);
    ((unsigned int*)(base + 1 * WPL))[ui] = (unsigned int)rl0 | ((unsigned int)rl1 << 16);
    ((unsigned int*)(base + 2 * WPL))[ui] = (unsigned int)ih0 | ((unsigned int)ih1 << 16);
    ((unsigned int*)(base + 3 * WPL))[ui] = (unsigned int)il0 | ((unsigned int)il1 << 16);
}

// ---------------------------------------------------------------------------
// Kernel 1: complex projection, split-bf16 MFMA (3-term per real product).
// K-chunk 32 -> 32 KB LDS -> 5 blocks/CU.
// Q/K out: hi/lo r/i planes [BH][S][64]; V out: pre-transposed [BH][64][S].
// ---------------------------------------------------------------------------
__global__ __launch_bounds__(256, 5)
void proj_kernel(const float2* __restrict__ qin, const float2* __restrict__ kin,
                 const float2* __restrict__ vin,
                 const unsigned short* __restrict__ WP,
                 const float2* __restrict__ bq, const float2* __restrict__ bk,
                 const float2* __restrict__ bv,
                 unsigned short* __restrict__ QG, unsigned short* __restrict__ KG,
                 unsigned short* __restrict__ VG) {
    const float2* X; const float2* bias; unsigned short* outP;
    const unsigned short* WM = WP + (size_t)blockIdx.z * 4 * WPL;
    if (blockIdx.z == 0)      { X = qin; bias = bq; outP = QG; }
    else if (blockIdx.z == 1) { X = kin; bias = bk; outP = KG; }
    else                      { X = vin; bias = bv; outP = VG; }
    const bool isV = (blockIdx.z == 2);

    __shared__ unsigned short Xs[4][2048];   // [rhi,rlo,ihi,ilo][64 m][32 d]
    __shared__ unsigned short Ws[4][2048];   // [rhi,rlo,ihi,ilo][64 e][32 d]

    const int tid  = threadIdx.x;
    const int w    = tid >> 6;
    const int lane = tid & 63;
    const int quad = lane >> 4;
    const int l15  = lane & 15;
    const int m0   = blockIdx.x * 64;
    const int h    = blockIdx.y;
    const int e0   = h * 64;

    const int srow = tid >> 2;          // 0..63
    const int sseg = (tid & 3) * 8;     // 0,8,16,24
    const int soff = srow * 32 + (sseg ^ ((srow & 3) << 3));

    f32x4 Sr[4], Si[4];
    #pragma unroll
    for (int i = 0; i < 4; ++i) { Sr[i] = (f32x4)0.f; Si[i] = (f32x4)0.f; }

    for (int dc = 0; dc < DD; dc += 32) {
        if (dc) __syncthreads();
        // --- X chunk: fp32 complex -> hi/lo r/i bf16 (8 complex / thread) ---
        {
            const float4* xp = (const float4*)(X + (size_t)(m0 + srow) * DD + dc + sseg);
            union { unsigned short u[8]; uint4 q; } rh, rl, ih, il;
            #pragma unroll
            for (int j = 0; j < 4; ++j) {
                float4 t = xp[j];
                int a = 2 * j, b2 = 2 * j + 1;
                rh.u[a]  = f2bf(t.x); rl.u[a]  = f2bf(t.x - bf2f(rh.u[a]));
                ih.u[a]  = f2bf(t.y); il.u[a]  = f2bf(t.y - bf2f(ih.u[a]));
                rh.u[b2] = f2bf(t.z); rl.u[b2] = f2bf(t.z - bf2f(rh.u[b2]));
                ih.u[b2] = f2bf(t.w); il.u[b2] = f2bf(t.w - bf2f(ih.u[b2]));
            }
            *(uint4*)&Xs[0][soff] = rh.q;
            *(uint4*)&Xs[1][soff] = rl.q;
            *(uint4*)&Xs[2][soff] = ih.q;
            *(uint4*)&Xs[3][soff] = il.q;
        }
        // --- W chunk: direct bf16 plane copies ---
        {
            const size_t wo = (size_t)(e0 + srow) * DD + dc + sseg;
            #pragma unroll
            for (int p = 0; p < 4; ++p)
                *(uint4*)&Ws[p][soff] = *(const uint4*)(WM + (size_t)p * WPL + wo);
        }
        __syncthreads();

        const int mrow = w * 16 + l15;
        const int dl   = quad * 8;
        short8 xrh = ld32(Xs[0], mrow, dl);
        short8 xrl = ld32(Xs[1], mrow, dl);
        short8 xih = ld32(Xs[2], mrow, dl);
        short8 xil = ld32(Xs[3], mrow, dl);
        short8 xmih = negbf(xih), xmil = negbf(xil);
        #pragma unroll
        for (int et = 0; et < 4; ++et) {
            const int er = et * 16 + l15;
            short8 wrh = ld32(Ws[0], er, dl);
            short8 wrl = ld32(Ws[1], er, dl);
            short8 wih = ld32(Ws[2], er, dl);
            short8 wil = ld32(Ws[3], er, dl);
            // Sr = XrWr - XiWi (3-term splits)
            MFMA(Sr[et], xrh,  wrh); MFMA(Sr[et], xrh,  wrl); MFMA(Sr[et], xrl,  wrh);
            MFMA(Sr[et], xmih, wih); MFMA(Sr[et], xmih, wil); MFMA(Sr[et], xmil, wih);
            // Si = XrWi + XiWr
            MFMA(Si[et], xrh,  wih); MFMA(Si[et], xrh,  wil); MFMA(Si[et], xrl,  wih);
            MFMA(Si[et], xih,  wrh); MFMA(Si[et], xih,  wrl); MFMA(Si[et], xil,  wrh);
        }
    }

    // epilogue: + bias, hi/lo split, write planes (V transposed)
    #pragma unroll
    for (int et = 0; et < 4; ++et) {
        const int col = et * 16 + l15;
        float2 bb = bias[e0 + col];
        #pragma unroll
        for (int reg = 0; reg < 4; ++reg) {
            int m = m0 + w * 16 + quad * 4 + reg;
            int b = m >> 10;
            int s = m & 1023;
            int bh = b * HH + h;
            float vr = Sr[et][reg] + bb.x;
            float vi = Si[et][reg] + bb.y;
            unsigned short rh = f2bf(vr), ih2 = f2bf(vi);
            unsigned short rl = f2bf(vr - bf2f(rh)), il2 = f2bf(vi - bf2f(ih2));
            size_t o = isV ? ((size_t)bh * DHD + col) * SS + s
                           : ((size_t)bh * SS + s) * DHD + col;
            outP[0 * PL + o] = rh;
            outP[1 * PL + o] = rl;
            outP[2 * PL + o] = ih2;
            outP[3 * PL + o] = il2;
        }
    }
}

// ---------------------------------------------------------------------------
// Kernel 2: MFMA flash attention, split-bf16 scores, dual fixed-max softmax.
// Round-3 shape (256 thr, k-tile 32, (256,2): no VGPR cap -> no spill).
// 1-D grid with XCD-aware decode: block n -> xcd=n&7, bh=xcd*4+(n>>7),
// qt=(n>>3)&15, so each XCD's resident blocks share only 4 bh (K+V 4 MB ~ L2).
// ---------------------------------------------------------------------------
__global__ __launch_bounds__(256, 2)
void attn_kernel(const unsigned short* __restrict__ QG, const unsigned short* __restrict__ KG,
                 const unsigned short* __restrict__ VG,
                 unsigned short* __restrict__ ObR, unsigned short* __restrict__ ObI) {
    __shared__ unsigned short Ks[4][2048];   // [rhi,rlo,ihi,ilo][32 k][64 d]
    __shared__ unsigned short Vt[4][2048];   // [rhi,rlo,ihi,ilo][64 d][32 k]
    __shared__ unsigned short Ps[2][4][512]; // [r,i][wave][16 q][32 k]

    const int n   = blockIdx.x;
    const int bh  = (n & 7) * 4 + (n >> 7);   // XCD-local bh group
    const int q0  = ((n >> 3) & 15) * 64;
    const int b   = bh >> 3;
    const int h   = bh & 7;

    const int tid  = threadIdx.x;
    const int w    = tid >> 6;
    const int lane = tid & 63;
    const int quad = lane >> 4;
    const int l15  = lane & 15;

    // Q fragments (hi/lo r/i) once from global, held in registers
    short8 qrh[2], qrl[2], qih[2], qil[2];
    #pragma unroll
    for (int kc = 0; kc < 2; ++kc) {
        size_t qb = ((size_t)bh * SS + q0 + w * 16 + l15) * DHD + kc * 32 + quad * 8;
        qrh[kc] = *(const short8*)(QG + 0 * PL + qb);
        qrl[kc] = *(const short8*)(QG + 1 * PL + qb);
        qih[kc] = *(const short8*)(QG + 2 * PL + qb);
        qil[kc] = *(const short8*)(QG + 3 * PL + qb);
    }

    f32x4 Arr[4], Ari[4], Air[4], Aii[4];
    #pragma unroll
    for (int i = 0; i < 4; ++i) { Arr[i] = (f32x4)0.f; Ari[i] = (f32x4)0.f; Air[i] = (f32x4)0.f; Aii[i] = (f32x4)0.f; }
    float lrp[4] = {0.f, 0.f, 0.f, 0.f}, lip[4] = {0.f, 0.f, 0.f, 0.f};

    unsigned short* PrW = Ps[0][w];
    unsigned short* PiW = Ps[1][w];

    for (int kt = 0; kt < SS; kt += 32) {
        if (kt) __syncthreads();
        // ---- staging: wave w handles plane w of K and V (all uint4) ----
        {
            const unsigned short* Kw = KG + (size_t)w * PL + ((size_t)bh * SS + kt) * DHD;
            const unsigned short* Vw = VG + (size_t)w * PL + (size_t)bh * DHD * SS + kt;
            unsigned short* KsW = Ks[w];
            unsigned short* VtW = Vt[w];
            #pragma unroll
            for (int it = 0; it < 4; ++it) {
                int idx = it * 64 + lane;
                int kr = idx >> 3, sg = (idx & 7) * 8;
                *(uint4*)&KsW[kr * 64 + (sg ^ ((kr & 7) << 3))] = *(const uint4*)(Kw + kr * 64 + sg);
                int dv = idx >> 2, sv = (idx & 3) * 8;
                *(uint4*)&VtW[dv * 32 + (sv ^ ((dv & 3) << 3))] = *(const uint4*)(Vw + (size_t)dv * SS + sv);
            }
        }
        __syncthreads();

        // ---- scores: split complex QK^T (K imag negated inline) ----
        f32x4 Sr[2], Si[2];
        Sr[0] = (f32x4)0.f; Sr[1] = (f32x4)0.f; Si[0] = (f32x4)0.f; Si[1] = (f32x4)0.f;
        #pragma unroll
        for (int kc = 0; kc < 2; ++kc) {
            const int dl = kc * 32 + quad * 8;
            #pragma unroll
            for (int nt = 0; nt < 2; ++nt) {
                const int kr = nt * 16 + l15;
                short8 krh = ld64(Ks[0], kr, dl);
                short8 krl = ld64(Ks[1], kr, dl);
                short8 kih = ld64(Ks[2], kr, dl);
                short8 kil = ld64(Ks[3], kr, dl);
                short8 kmih = negbf(kih), kmil = negbf(kil);
                // Sr = QrKr - QiKi
                MFMA(Sr[nt], qrh[kc], krh);  MFMA(Sr[nt], qrh[kc], krl);  MFMA(Sr[nt], qrl[kc], krh);
                MFMA(Sr[nt], qih[kc], kmih); MFMA(Sr[nt], qih[kc], kmil); MFMA(Sr[nt], qil[kc], kmih);
                // Si = QrKi + QiKr
                MFMA(Si[nt], qrh[kc], kih);  MFMA(Si[nt], qrh[kc], kil);  MFMA(Si[nt], qrl[kc], kih);
                MFMA(Si[nt], qih[kc], krh);  MFMA(Si[nt], qih[kc], krl);  MFMA(Si[nt], qil[kc], krh);
            }
        }

        // ---- dual softmax numerators (|s/8| < ~6, fixed max): P = exp(s/8) ----
        #pragma unroll
        for (int nt = 0; nt < 2; ++nt) {
            #pragma unroll
            for (int reg = 0; reg < 4; ++reg) {
                float pr = __expf(Sr[nt][reg] * 0.125f);
                float pi = __expf(Si[nt][reg] * 0.125f);
                unsigned short ph = f2bf(pr), pih2 = f2bf(pi);
                lrp[reg] += bf2f(ph);          // l from rounded p: consistent weights
                lip[reg] += bf2f(pih2);
                int qq = quad * 4 + reg;
                int kcol = nt * 16 + l15;
                PrW[qq * 32 + (kcol ^ ((qq & 3) << 3))] = ph;
                PiW[qq * 32 + (kcol ^ ((qq & 3) << 3))] = pih2;
            }
        }
        // wave-private LDS round-trip; compiler inserts lgkmcnt, no barrier

        // ---- PV: P (single bf16) x V (hi/lo) ----
        {
            const int kl = quad * 8;
            short8 prF = ld32(PrW, l15, kl);
            short8 piF = ld32(PiW, l15, kl);
            #pragma unroll
            for (int dt = 0; dt < 4; ++dt) {
                const int d = dt * 16 + l15;
                short8 vrh = ld32(Vt[0], d, kl);
                short8 vrl = ld32(Vt[1], d, kl);
                short8 vih = ld32(Vt[2], d, kl);
                short8 vil = ld32(Vt[3], d, kl);
                MFMA(Arr[dt], prF, vrh); MFMA(Arr[dt], prF, vrl);
                MFMA(Ari[dt], prF, vih); MFMA(Ari[dt], prF, vil);
                MFMA(Air[dt], piF, vrh); MFMA(Air[dt], piF, vrl);
                MFMA(Aii[dt], piF, vih); MFMA(Aii[dt], piF, vil);
            }
        }
    }

    // ---- reduce l across the 16 lanes of each quad, combine, store bf16 ----
    float ir[4], ii[4];
    #pragma unroll
    for (int reg = 0; reg < 4; ++reg) {
        float a = lrp[reg], c = lip[reg];
        #pragma unroll
        for (int mk = 1; mk < 16; mk <<= 1) {
            a += __shfl_xor(a, mk);
            c += __shfl_xor(c, mk);
        }
        ir[reg] = 1.f / a;
        ii[reg] = 1.f / c;
    }
    #pragma unroll
    for (int dt = 0; dt < 4; ++dt) {
        #pragma unroll
        for (int reg = 0; reg < 4; ++reg) {
            int q   = q0 + w * 16 + quad * 4 + reg;
            int col = h * DHD + dt * 16 + l15;
            float outr = Arr[dt][reg] * ir[reg] - Aii[dt][reg] * ii[reg];
            float outi = Ari[dt][reg] * ir[reg] + Air[dt][reg] * ii[reg];
            size_t o = ((size_t)b * SS + q) * DD + col;
            ObR[o] = f2bf(outr);
            ObI[o] = f2bf(outi);
        }
    }
}

// ---------------------------------------------------------------------------
// Kernel 3: residual + dual LayerNorm over D (biased var, eps inside sqrt)
// ---------------------------------------------------------------------------
__global__ __launch_bounds__(256)
void ln_kernel(const unsigned short* __restrict__ OrP, const unsigned short* __restrict__ OiP,
               const float2* __restrict__ Qin,
               const float* __restrict__ gr, const float* __restrict__ br,
               const float* __restrict__ gi, const float* __restrict__ bi,
               float2* __restrict__ out) {
    const int row = blockIdx.x;           // b*S + s
    const int tid = threadIdx.x;
    const size_t base = (size_t)row * DD;
    const int e0 = 2 * tid, e1 = 2 * tid + 1;

    unsigned int ar = *(const unsigned int*)(OrP + base + e0);
    unsigned int ai = *(const unsigned int*)(OiP + base + e0);
    float2 r0 = Qin[base + e0];
    float2 r1 = Qin[base + e1];
    float xr0 = __uint_as_float(ar << 16) + r0.x;
    float xr1 = __uint_as_float(ar & 0xFFFF0000u) + r1.x;
    float xi0 = __uint_as_float(ai << 16) + r0.y;
    float xi1 = __uint_as_float(ai & 0xFFFF0000u) + r1.y;

    float sr = xr0 + xr1;
    float si = xi0 + xi1;
    float qr = xr0 * xr0 + xr1 * xr1;
    float qi = xi0 * xi0 + xi1 * xi1;
    #pragma unroll
    for (int off = 32; off > 0; off >>= 1) {
        sr += __shfl_down(sr, off);
        si += __shfl_down(si, off);
        qr += __shfl_down(qr, off);
        qi += __shfl_down(qi, off);
    }
    __shared__ float red[4][4];
    __shared__ float stat[4];
    int lane = tid & 63, wid = tid >> 6;
    if (lane == 0) { red[wid][0] = sr; red[wid][1] = si; red[wid][2] = qr; red[wid][3] = qi; }
    __syncthreads();
    if (tid == 0) {
        sr = red[0][0] + red[1][0] + red[2][0] + red[3][0];
        si = red[0][1] + red[1][1] + red[2][1] + red[3][1];
        qr = red[0][2] + red[1][2] + red[2][2] + red[3][2];
        qi = red[0][3] + red[1][3] + red[2][3] + red[3][3];
        float mur = sr * (1.f / DD), mui = si * (1.f / DD);
        float vr = qr * (1.f / DD) - mur * mur;
        float vi = qi * (1.f / DD) - mui * mui;
        stat[0] = mur; stat[1] = mui;
        stat[2] = rsqrtf(vr + LN_EPS); stat[3] = rsqrtf(vi + LN_EPS);
    }
    __syncthreads();
    float mur = stat[0], mui = stat[1], rsr = stat[2], rsi = stat[3];
    out[base + e0] = make_float2((xr0 - mur) * rsr * gr[e0] + br[e0],
                                 (xi0 - mui) * rsi * gi[e0] + bi[e0]);
    out[base + e1] = make_float2((xr1 - mur) * rsr * gr[e1] + br[e1],
                                 (xi1 - mui) * rsi * gi[e1] + bi[e1]);
}

// ---------------------------------------------------------------------------
extern "C" void kernel_launch(void* const* d_in, const int* in_sizes, int n_in,
                              void* d_out, int out_size, void* d_ws, size_t ws_size,
                              hipStream_t stream) {
    const float2* q  = (const float2*)d_in[0];
    const float2* k  = (const float2*)d_in[1];
    const float2* v  = (const float2*)d_in[2];
    const float2* Wq = (const float2*)d_in[3];
    const float2* bq = (const float2*)d_in[4];
    const float2* Wk = (const float2*)d_in[5];
    const float2* bk = (const float2*)d_in[6];
    const float2* Wv = (const float2*)d_in[7];
    const float2* bv = (const float2*)d_in[8];
    const float*  gr = (const float*)d_in[9];
    const float*  br = (const float*)d_in[10];
    const float*  gi = (const float*)d_in[11];
    const float*  bi = (const float*)d_in[12];

    // workspace layout (bf16 elements): W planes, Q planes, K planes, V planes, Ob
    unsigned short* WP  = (unsigned short*)d_ws;           // 3*4*WPL
    unsigned short* QG  = WP + (size_t)3 * 4 * WPL;        // 4*PL  [BH][S][64]
    unsigned short* KG  = QG + (size_t)4 * PL;             // 4*PL  [BH][S][64]
    unsigned short* VG  = KG + (size_t)4 * PL;             // 4*PL  [BH][64][S] (transposed)
    unsigned short* ObR = VG + (size_t)4 * PL;             // PL    [B*S*D]
    unsigned short* ObI = ObR + (size_t)PL;                // PL

    wsplit_kernel<<<dim3(512, 3), 256, 0, stream>>>(Wq, Wk, Wv, WP);
    proj_kernel<<<dim3(64, 8, 3), 256, 0, stream>>>(q, k, v, WP, bq, bk, bv, QG, KG, VG);
    attn_kernel<<<dim3(512), 256, 0, stream>>>(QG, KG, VG, ObR, ObI);
    ln_kernel<<<dim3(BB * SS), 256, 0, stream>>>(ObR, ObI, q, gr, br, gi, bi, (float2*)d_out);
}

// Round 6
// 246.864 us; speedup vs baseline: 1.7830x; 1.2807x over previous
//
#include <hip/hip_runtime.h>
#include <math.h>

#define BB  4
#define SS  1024
#define DD  512
#define HH  8
#define DHD 64
#define PL  2097152      // elements per Q/K/V/Ob plane
#define WPL 262144       // elements per W plane

constexpr float LN_EPS = 1e-5f;

using half8 = __attribute__((ext_vector_type(8))) _Float16;
using f32x4 = __attribute__((ext_vector_type(4))) float;

__device__ __forceinline__ half8 negh(half8 a) {
    union { half8 h; unsigned int u[4]; } t;
    t.h = a;
    #pragma unroll
    for (int i = 0; i < 4; ++i) t.u[i] ^= 0x80008000u;
    return t.h;
}
// 64-wide swizzled rows (XOR (row&7)<<3, 8-half granules): conflict-free b128
__device__ __forceinline__ half8 ldh64(const unsigned short* p, int row, int col) {
    return *(const half8*)(p + row * 64 + (col ^ ((row & 7) << 3)));
}
// 40-wide padded rows (20 banks/row, period 8 -> 2-way max): no XOR needed
__device__ __forceinline__ half8 ldh40(const unsigned short* p, int row, int col) {
    return *(const half8*)(p + row * 40 + col);
}
#define MFMA16(acc, a, b) acc = __builtin_amdgcn_mfma_f32_16x16x32_f16(a, b, acc, 0, 0, 0)

// ---------------------------------------------------------------------------
// Kernel 0: convert Wq/Wk/Wv (fp32 complex [512][512]) to fp16 r/i planes.
// ---------------------------------------------------------------------------
__global__ __launch_bounds__(256)
void whalf_kernel(const float2* __restrict__ Wq, const float2* __restrict__ Wk,
                  const float2* __restrict__ Wv, unsigned short* __restrict__ WP) {
    const int mat = blockIdx.y;
    const float2* W = mat == 0 ? Wq : (mat == 1 ? Wk : Wv);
    unsigned short* base = WP + (size_t)mat * 2 * WPL;
    const int idx = (blockIdx.x * 256 + threadIdx.x) * 2;   // complex index, 2/thread
    float4 t = *(const float4*)(W + idx);
    union { _Float16 h[2]; unsigned int u; } r, i;
    r.h[0] = (_Float16)t.x; r.h[1] = (_Float16)t.z;
    i.h[0] = (_Float16)t.y; i.h[1] = (_Float16)t.w;
    ((unsigned int*)(base + 0 * WPL))[idx >> 1] = r.u;
    ((unsigned int*)(base + 1 * WPL))[idx >> 1] = i.u;
}

// ---------------------------------------------------------------------------
// Kernel 1: complex projection, single-fp16 MFMA (4 MFMAs per complex group).
// K-chunk 64, 64-wide swizzled LDS rows (0-conflict), 32 KB -> 5 blocks/CU.
// Q/K out: fp16 r/i planes [BH][S][64]; V out: pre-transposed [BH][64][S].
// ---------------------------------------------------------------------------
__global__ __launch_bounds__(256, 5)
void proj_kernel(const float2* __restrict__ qin, const float2* __restrict__ kin,
                 const float2* __restrict__ vin,
                 const unsigned short* __restrict__ WP,
                 const float2* __restrict__ bq, const float2* __restrict__ bk,
                 const float2* __restrict__ bv,
                 unsigned short* __restrict__ QG, unsigned short* __restrict__ KG,
                 unsigned short* __restrict__ VG) {
    const float2* X; const float2* bias; unsigned short* outP;
    const unsigned short* WM = WP + (size_t)blockIdx.z * 2 * WPL;
    if (blockIdx.z == 0)      { X = qin; bias = bq; outP = QG; }
    else if (blockIdx.z == 1) { X = kin; bias = bk; outP = KG; }
    else                      { X = vin; bias = bv; outP = VG; }
    const bool isV = (blockIdx.z == 2);

    __shared__ unsigned short Xs[2][4096];   // [r,i][64 m][64 d] swizzled
    __shared__ unsigned short Ws[2][4096];   // [r,i][64 e][64 d] swizzled

    const int tid  = threadIdx.x;
    const int w    = tid >> 6;
    const int lane = tid & 63;
    const int quad = lane >> 4;
    const int l15  = lane & 15;
    const int m0   = blockIdx.x * 64;
    const int h    = blockIdx.y;
    const int e0   = h * 64;

    const int sm  = tid & 63;           // staging row
    const int d0  = (tid >> 6) * 16;    // 16-half segment per wave
    const int ssw = (sm & 7) << 3;

    f32x4 Sr[4], Si[4];
    #pragma unroll
    for (int i = 0; i < 4; ++i) { Sr[i] = (f32x4)0.f; Si[i] = (f32x4)0.f; }

    for (int dc = 0; dc < DD; dc += 64) {
        if (dc) __syncthreads();
        // --- X chunk: fp32 complex -> fp16 r/i (16 complex / thread) ---
        {
            const float4* xp = (const float4*)(X + (size_t)(m0 + sm) * DD + dc + d0);
            union { _Float16 h[16]; uint4 q[2]; } xr, xi;
            #pragma unroll
            for (int j = 0; j < 8; ++j) {
                float4 t = xp[j];
                xr.h[2*j]   = (_Float16)t.x; xi.h[2*j]   = (_Float16)t.y;
                xr.h[2*j+1] = (_Float16)t.z; xi.h[2*j+1] = (_Float16)t.w;
            }
            const int o0 = sm * 64 + (d0 ^ ssw), o1 = sm * 64 + ((d0 + 8) ^ ssw);
            *(uint4*)&Xs[0][o0] = xr.q[0]; *(uint4*)&Xs[0][o1] = xr.q[1];
            *(uint4*)&Xs[1][o0] = xi.q[0]; *(uint4*)&Xs[1][o1] = xi.q[1];
        }
        // --- W chunk: direct fp16 plane copies ---
        {
            const size_t wo = (size_t)(e0 + sm) * DD + dc + d0;
            const int o0 = sm * 64 + (d0 ^ ssw), o1 = sm * 64 + ((d0 + 8) ^ ssw);
            *(uint4*)&Ws[0][o0] = *(const uint4*)(WM + 0 * WPL + wo);
            *(uint4*)&Ws[0][o1] = *(const uint4*)(WM + 0 * WPL + wo + 8);
            *(uint4*)&Ws[1][o0] = *(const uint4*)(WM + 1 * WPL + wo);
            *(uint4*)&Ws[1][o1] = *(const uint4*)(WM + 1 * WPL + wo + 8);
        }
        __syncthreads();

        const int mrow = w * 16 + l15;
        #pragma unroll
        for (int kc = 0; kc < 2; ++kc) {
            const int dl = kc * 32 + quad * 8;
            half8 xr  = ldh64(Xs[0], mrow, dl);
            half8 xi  = ldh64(Xs[1], mrow, dl);
            half8 xmi = negh(xi);
            #pragma unroll
            for (int et = 0; et < 4; ++et) {
                const int er = et * 16 + l15;
                half8 wr = ldh64(Ws[0], er, dl);
                half8 wi = ldh64(Ws[1], er, dl);
                MFMA16(Sr[et], xr,  wr);   // Sr = XrWr - XiWi
                MFMA16(Sr[et], xmi, wi);
                MFMA16(Si[et], xr,  wi);   // Si = XrWi + XiWr
                MFMA16(Si[et], xi,  wr);
            }
        }
    }

    // epilogue: + bias, fp16, write planes (V transposed)
    #pragma unroll
    for (int et = 0; et < 4; ++et) {
        const int col = et * 16 + l15;
        float2 bb = bias[e0 + col];
        #pragma unroll
        for (int reg = 0; reg < 4; ++reg) {
            int m = m0 + w * 16 + quad * 4 + reg;
            int b = m >> 10;
            int s = m & 1023;
            int bh = b * HH + h;
            union { _Float16 h; unsigned short u; } cr, ci;
            cr.h = (_Float16)(Sr[et][reg] + bb.x);
            ci.h = (_Float16)(Si[et][reg] + bb.y);
            size_t o = isV ? ((size_t)bh * DHD + col) * SS + s
                           : ((size_t)bh * SS + s) * DHD + col;
            outP[0 * PL + o] = cr.u;
            outP[1 * PL + o] = ci.u;
        }
    }
}

// ---------------------------------------------------------------------------
// Kernel 2: fp16 MFMA flash attention, dual fixed-max softmax.
// 256 thr, k-tile 32, XCD-aware block decode. LDS: K 64-wide swizzled (0-conf),
// V^T/P 40-padded rows (2-way max). (256,3): no VGPR spill.
// ---------------------------------------------------------------------------
__global__ __launch_bounds__(256, 3)
void attn_kernel(const unsigned short* __restrict__ QG, const unsigned short* __restrict__ KG,
                 const unsigned short* __restrict__ VG,
                 unsigned short* __restrict__ ObR, unsigned short* __restrict__ ObI) {
    __shared__ unsigned short Ks[2][2048];     // [r,i][32 k][64 d] swizzled
    __shared__ unsigned short Vt[2][2560];     // [r,i][64 d][40(32 k)] padded
    __shared__ unsigned short Ps[2][4][640];   // [r,i][wave][16 q][40(32 k)] padded

    const int n   = blockIdx.x;
    const int bh  = (n & 7) * 4 + (n >> 7);    // XCD-local bh group
    const int q0  = ((n >> 3) & 15) * 64;
    const int b   = bh >> 3;
    const int h   = bh & 7;

    const int tid  = threadIdx.x;
    const int w    = tid >> 6;
    const int lane = tid & 63;
    const int quad = lane >> 4;
    const int l15  = lane & 15;

    // Q fragments (r/i) once from global, held in registers
    half8 qr[2], qi[2], qmi[2];
    #pragma unroll
    for (int kc = 0; kc < 2; ++kc) {
        size_t qb = ((size_t)bh * SS + q0 + w * 16 + l15) * DHD + kc * 32 + quad * 8;
        qr[kc]  = *(const half8*)(QG + 0 * PL + qb);
        qi[kc]  = *(const half8*)(QG + 1 * PL + qb);
        qmi[kc] = negh(qi[kc]);
    }

    f32x4 Arr[4], Ari[4], Air[4], Aii[4];
    #pragma unroll
    for (int i = 0; i < 4; ++i) { Arr[i] = (f32x4)0.f; Ari[i] = (f32x4)0.f; Air[i] = (f32x4)0.f; Aii[i] = (f32x4)0.f; }
    float lrp[4] = {0.f, 0.f, 0.f, 0.f}, lip[4] = {0.f, 0.f, 0.f, 0.f};

    unsigned short* PrW = Ps[0][w];
    unsigned short* PiW = Ps[1][w];

    // staging indices
    const int kr = tid >> 3, sg = (tid & 7) * 8;   // K: [32k][64d]
    const int dv = tid >> 2, sv = (tid & 3) * 8;   // V: [64d][32k]

    for (int kt = 0; kt < SS; kt += 32) {
        if (kt) __syncthreads();
        #pragma unroll
        for (int p = 0; p < 2; ++p) {
            *(uint4*)&Ks[p][kr * 64 + (sg ^ ((kr & 7) << 3))] =
                *(const uint4*)(KG + (size_t)p * PL + ((size_t)bh * SS + kt + kr) * DHD + sg);
            *(uint4*)&Vt[p][dv * 40 + sv] =
                *(const uint4*)(VG + (size_t)p * PL + ((size_t)bh * DHD + dv) * SS + kt + sv);
        }
        __syncthreads();

        // ---- scores: complex QK^T ----
        f32x4 Sr[2], Si[2];
        Sr[0] = (f32x4)0.f; Sr[1] = (f32x4)0.f; Si[0] = (f32x4)0.f; Si[1] = (f32x4)0.f;
        #pragma unroll
        for (int kc = 0; kc < 2; ++kc) {
            const int dl = kc * 32 + quad * 8;
            #pragma unroll
            for (int nt = 0; nt < 2; ++nt) {
                const int krow = nt * 16 + l15;
                half8 krF = ldh64(Ks[0], krow, dl);
                half8 kiF = ldh64(Ks[1], krow, dl);
                MFMA16(Sr[nt], qr[kc],  krF);   // Sr = QrKr - QiKi
                MFMA16(Sr[nt], qmi[kc], kiF);
                MFMA16(Si[nt], qr[kc],  kiF);   // Si = QrKi + QiKr
                MFMA16(Si[nt], qi[kc],  krF);
            }
        }

        // ---- dual softmax numerators (|s/8| < ~6, fixed max): P = exp(s/8) ----
        #pragma unroll
        for (int nt = 0; nt < 2; ++nt) {
            #pragma unroll
            for (int reg = 0; reg < 4; ++reg) {
                union { _Float16 h; unsigned short u; } cr, ci;
                cr.h = (_Float16)__expf(Sr[nt][reg] * 0.125f);
                ci.h = (_Float16)__expf(Si[nt][reg] * 0.125f);
                lrp[reg] += (float)cr.h;       // l from rounded p: consistent weights
                lip[reg] += (float)ci.h;
                int qq = quad * 4 + reg;
                int kcol = nt * 16 + l15;
                PrW[qq * 40 + kcol] = cr.u;
                PiW[qq * 40 + kcol] = ci.u;
            }
        }
        // wave-private LDS round-trip; compiler inserts lgkmcnt, no barrier

        // ---- PV: P x V (r/i) ----
        {
            const int kl = quad * 8;
            half8 prF = ldh40(PrW, l15, kl);
            half8 piF = ldh40(PiW, l15, kl);
            #pragma unroll
            for (int dt = 0; dt < 4; ++dt) {
                const int d = dt * 16 + l15;
                half8 vrF = ldh40(Vt[0], d, kl);
                half8 viF = ldh40(Vt[1], d, kl);
                MFMA16(Arr[dt], prF, vrF);
                MFMA16(Ari[dt], prF, viF);
                MFMA16(Air[dt], piF, vrF);
                MFMA16(Aii[dt], piF, viF);
            }
        }
    }

    // ---- reduce l across the 16 lanes of each quad, combine, store fp16 ----
    float ir[4], ii[4];
    #pragma unroll
    for (int reg = 0; reg < 4; ++reg) {
        float a = lrp[reg], c = lip[reg];
        #pragma unroll
        for (int mk = 1; mk < 16; mk <<= 1) {
            a += __shfl_xor(a, mk);
            c += __shfl_xor(c, mk);
        }
        ir[reg] = 1.f / a;
        ii[reg] = 1.f / c;
    }
    #pragma unroll
    for (int dt = 0; dt < 4; ++dt) {
        #pragma unroll
        for (int reg = 0; reg < 4; ++reg) {
            int q   = q0 + w * 16 + quad * 4 + reg;
            int col = h * DHD + dt * 16 + l15;
            union { _Float16 h; unsigned short u; } cr, ci;
            cr.h = (_Float16)(Arr[dt][reg] * ir[reg] - Aii[dt][reg] * ii[reg]);
            ci.h = (_Float16)(Ari[dt][reg] * ir[reg] + Air[dt][reg] * ii[reg]);
            size_t o = ((size_t)b * SS + q) * DD + col;
            ObR[o] = cr.u;
            ObI[o] = ci.u;
        }
    }
}

// ---------------------------------------------------------------------------
// Kernel 3: residual + dual LayerNorm over D (biased var, eps inside sqrt)
// ---------------------------------------------------------------------------
__global__ __launch_bounds__(256)
void ln_kernel(const unsigned short* __restrict__ OrP, const unsigned short* __restrict__ OiP,
               const float2* __restrict__ Qin,
               const float* __restrict__ gr, const float* __restrict__ br,
               const float* __restrict__ gi, const float* __restrict__ bi,
               float2* __restrict__ out) {
    const int row = blockIdx.x;           // b*S + s
    const int tid = threadIdx.x;
    const size_t base = (size_t)row * DD;
    const int e0 = 2 * tid, e1 = 2 * tid + 1;

    union { unsigned int u; _Float16 h[2]; } tr, ti;
    tr.u = *(const unsigned int*)(OrP + base + e0);
    ti.u = *(const unsigned int*)(OiP + base + e0);
    float2 r0 = Qin[base + e0];
    float2 r1 = Qin[base + e1];
    float xr0 = (float)tr.h[0] + r0.x;
    float xr1 = (float)tr.h[1] + r1.x;
    float xi0 = (float)ti.h[0] + r0.y;
    float xi1 = (float)ti.h[1] + r1.y;

    float sr = xr0 + xr1;
    float si = xi0 + xi1;
    float qr = xr0 * xr0 + xr1 * xr1;
    float qi = xi0 * xi0 + xi1 * xi1;
    #pragma unroll
    for (int off = 32; off > 0; off >>= 1) {
        sr += __shfl_down(sr, off);
        si += __shfl_down(si, off);
        qr += __shfl_down(qr, off);
        qi += __shfl_down(qi, off);
    }
    __shared__ float red[4][4];
    __shared__ float stat[4];
    int lane = tid & 63, wid = tid >> 6;
    if (lane == 0) { red[wid][0] = sr; red[wid][1] = si; red[wid][2] = qr; red[wid][3] = qi; }
    __syncthreads();
    if (tid == 0) {
        sr = red[0][0] + red[1][0] + red[2][0] + red[3][0];
        si = red[0][1] + red[1][1] + red[2][1] + red[3][1];
        qr = red[0][2] + red[1][2] + red[2][2] + red[3][2];
        qi = red[0][3] + red[1][3] + red[2][3] + red[3][3];
        float mur = sr * (1.f / DD), mui = si * (1.f / DD);
        float vr = qr * (1.f / DD) - mur * mur;
        float vi = qi * (1.f / DD) - mui * mui;
        stat[0] = mur; stat[1] = mui;
        stat[2] = rsqrtf(vr + LN_EPS); stat[3] = rsqrtf(vi + LN_EPS);
    }
    __syncthreads();
    float mur = stat[0], mui = stat[1], rsr = stat[2], rsi = stat[3];
    out[base + e0] = make_float2((xr0 - mur) * rsr * gr[e0] + br[e0],
                                 (xi0 - mui) * rsi * gi[e0] + bi[e0]);
    out[base + e1] = make_float2((xr1 - mur) * rsr * gr[e1] + br[e1],
                                 (xi1 - mui) * rsi * gi[e1] + bi[e1]);
}

// ---------------------------------------------------------------------------
extern "C" void kernel_launch(void* const* d_in, const int* in_sizes, int n_in,
                              void* d_out, int out_size, void* d_ws, size_t ws_size,
                              hipStream_t stream) {
    const float2* q  = (const float2*)d_in[0];
    const float2* k  = (const float2*)d_in[1];
    const float2* v  = (const float2*)d_in[2];
    const float2* Wq = (const float2*)d_in[3];
    const float2* bq = (const float2*)d_in[4];
    const float2* Wk = (const float2*)d_in[5];
    const float2* bk = (const float2*)d_in[6];
    const float2* Wv = (const float2*)d_in[7];
    const float2* bv = (const float2*)d_in[8];
    const float*  gr = (const float*)d_in[9];
    const float*  br = (const float*)d_in[10];
    const float*  gi = (const float*)d_in[11];
    const float*  bi = (const float*)d_in[12];

    // workspace layout (fp16 elements): W planes, Q planes, K planes, V planes, Ob
    unsigned short* WP  = (unsigned short*)d_ws;           // 3*2*WPL
    unsigned short* QG  = WP + (size_t)3 * 2 * WPL;        // 2*PL  [BH][S][64]
    unsigned short* KG  = QG + (size_t)2 * PL;             // 2*PL  [BH][S][64]
    unsigned short* VG  = KG + (size_t)2 * PL;             // 2*PL  [BH][64][S] (transposed)
    unsigned short* ObR = VG + (size_t)2 * PL;             // PL    [B*S*D]
    unsigned short* ObI = ObR + (size_t)PL;                // PL    (~37 MB total)

    whalf_kernel<<<dim3(512, 3), 256, 0, stream>>>(Wq, Wk, Wv, WP);
    proj_kernel<<<dim3(64, 8, 3), 256, 0, stream>>>(q, k, v, WP, bq, bk, bv, QG, KG, VG);
    attn_kernel<<<dim3(512), 256, 0, stream>>>(QG, KG, VG, ObR, ObI);
    ln_kernel<<<dim3(BB * SS), 256, 0, stream>>>(ObR, ObI, q, gr, br, gi, bi, (float2*)d_out);
}

// Round 7
// 225.625 us; speedup vs baseline: 1.9509x; 1.0941x over previous
//
#include <hip/hip_runtime.h>
#include <math.h>

#define BB  4
#define SS  1024
#define DD  512
#define HH  8
#define DHD 64
#define PL  2097152      // elements per Q/K/V/Ob plane (also B*S*D)
#define WPL 262144       // elements per W plane

constexpr float LN_EPS = 1e-5f;

using half8 = __attribute__((ext_vector_type(8))) _Float16;
using f32x4 = __attribute__((ext_vector_type(4))) float;

__device__ __forceinline__ half8 negh(half8 a) {
    union { half8 h; unsigned int u[4]; } t;
    t.h = a;
    #pragma unroll
    for (int i = 0; i < 4; ++i) t.u[i] ^= 0x80008000u;
    return t.h;
}
// 64-wide swizzled rows (XOR (row&7)<<3, 8-half granules): conflict-free b128
__device__ __forceinline__ half8 ldh64(const unsigned short* p, int row, int col) {
    return *(const half8*)(p + row * 64 + (col ^ ((row & 7) << 3)));
}
// 40-wide padded rows (20 banks/row, period 8 -> 2-way max): no XOR needed
__device__ __forceinline__ half8 ldh40(const unsigned short* p, int row, int col) {
    return *(const half8*)(p + row * 40 + col);
}
#define MFMA16(acc, a, b) acc = __builtin_amdgcn_mfma_f32_16x16x32_f16(a, b, acc, 0, 0, 0)

// ---------------------------------------------------------------------------
// Kernel 0: fp32 complex -> fp16 r/i planes (used for q/k/v inputs and W).
// blockIdx.y selects the source tensor; dst gets 2 planes per tensor.
// ---------------------------------------------------------------------------
__global__ __launch_bounds__(256)
void cvt_kernel(const float2* __restrict__ s0, const float2* __restrict__ s1,
                const float2* __restrict__ s2, unsigned short* __restrict__ dst,
                int planeElems) {
    const int z = blockIdx.y;
    const float2* src = z == 0 ? s0 : (z == 1 ? s1 : s2);
    unsigned short* base = dst + (size_t)z * 2 * planeElems;
    const int idx = (blockIdx.x * 256 + threadIdx.x) * 2;   // complex index
    float4 t = *(const float4*)(src + idx);
    union { _Float16 h[2]; unsigned int u; } r, i;
    r.h[0] = (_Float16)t.x; r.h[1] = (_Float16)t.z;
    i.h[0] = (_Float16)t.y; i.h[1] = (_Float16)t.w;
    ((unsigned int*)(base))[idx >> 1] = r.u;
    ((unsigned int*)(base + planeElems))[idx >> 1] = i.u;
}

// ---------------------------------------------------------------------------
// Kernel 1: complex projection, single-fp16 MFMA (4 MFMAs per complex group).
// Inputs pre-converted fp16 planes -> staging is pure coalesced uint4 copies:
// per instr a wave reads 8 rows x 128 B contiguous (16 lines); LDS write at
// granule g^(row&7) -> 2-way max per 16-lane phase (free).
// K-chunk 64, 32 KB LDS -> 5 blocks/CU.
// Q/K out: fp16 r/i planes [BH][S][64]; V out: pre-transposed [BH][64][S].
// ---------------------------------------------------------------------------
__global__ __launch_bounds__(256, 5)
void proj_kernel(const unsigned short* __restrict__ XP,
                 const unsigned short* __restrict__ WP,
                 const float2* __restrict__ bq, const float2* __restrict__ bk,
                 const float2* __restrict__ bv,
                 unsigned short* __restrict__ QG, unsigned short* __restrict__ KG,
                 unsigned short* __restrict__ VG) {
    const unsigned short* XR = XP + (size_t)blockIdx.z * 2 * PL;
    const unsigned short* XI = XR + PL;
    const unsigned short* WR = WP + (size_t)blockIdx.z * 2 * WPL;
    const unsigned short* WI = WR + WPL;
    const float2* bias; unsigned short* outP;
    if (blockIdx.z == 0)      { bias = bq; outP = QG; }
    else if (blockIdx.z == 1) { bias = bk; outP = KG; }
    else                      { bias = bv; outP = VG; }
    const bool isV = (blockIdx.z == 2);

    __shared__ unsigned short Xs[2][4096];   // [r,i][64 m][64 d] swizzled
    __shared__ unsigned short Ws[2][4096];   // [r,i][64 e][64 d] swizzled

    const int tid  = threadIdx.x;
    const int w    = tid >> 6;
    const int lane = tid & 63;
    const int quad = lane >> 4;
    const int l15  = lane & 15;
    const int m0   = blockIdx.x * 64;
    const int h    = blockIdx.y;
    const int e0   = h * 64;

    const int r8 = tid >> 3;        // 0..31 (staging row base)
    const int g8 = tid & 7;         // granule 0..7 (8 halfs)

    f32x4 Sr[4], Si[4];
    #pragma unroll
    for (int i = 0; i < 4; ++i) { Sr[i] = (f32x4)0.f; Si[i] = (f32x4)0.f; }

    for (int dc = 0; dc < DD; dc += 64) {
        if (dc) __syncthreads();
        #pragma unroll
        for (int it = 0; it < 2; ++it) {
            const int row = it * 32 + r8;
            const int off = row * 64 + ((g8 ^ (row & 7)) << 3);
            const size_t xo = (size_t)(m0 + row) * DD + dc + g8 * 8;
            const size_t wo = (size_t)(e0 + row) * DD + dc + g8 * 8;
            *(uint4*)&Xs[0][off] = *(const uint4*)(XR + xo);
            *(uint4*)&Xs[1][off] = *(const uint4*)(XI + xo);
            *(uint4*)&Ws[0][off] = *(const uint4*)(WR + wo);
            *(uint4*)&Ws[1][off] = *(const uint4*)(WI + wo);
        }
        __syncthreads();

        const int mrow = w * 16 + l15;
        #pragma unroll
        for (int kc = 0; kc < 2; ++kc) {
            const int dl = kc * 32 + quad * 8;
            half8 xr  = ldh64(Xs[0], mrow, dl);
            half8 xi  = ldh64(Xs[1], mrow, dl);
            half8 xmi = negh(xi);
            #pragma unroll
            for (int et = 0; et < 4; ++et) {
                const int er = et * 16 + l15;
                half8 wr = ldh64(Ws[0], er, dl);
                half8 wi = ldh64(Ws[1], er, dl);
                MFMA16(Sr[et], xr,  wr);   // Sr = XrWr - XiWi
                MFMA16(Sr[et], xmi, wi);
                MFMA16(Si[et], xr,  wi);   // Si = XrWi + XiWr
                MFMA16(Si[et], xi,  wr);
            }
        }
    }

    // epilogue: + bias, fp16, write planes (V transposed)
    #pragma unroll
    for (int et = 0; et < 4; ++et) {
        const int col = et * 16 + l15;
        float2 bb = bias[e0 + col];
        #pragma unroll
        for (int reg = 0; reg < 4; ++reg) {
            int m = m0 + w * 16 + quad * 4 + reg;
            int b = m >> 10;
            int s = m & 1023;
            int bh = b * HH + h;
            union { _Float16 h; unsigned short u; } cr, ci;
            cr.h = (_Float16)(Sr[et][reg] + bb.x);
            ci.h = (_Float16)(Si[et][reg] + bb.y);
            size_t o = isV ? ((size_t)bh * DHD + col) * SS + s
                           : ((size_t)bh * SS + s) * DHD + col;
            outP[0 * PL + o] = cr.u;
            outP[1 * PL + o] = ci.u;
        }
    }
}

// ---------------------------------------------------------------------------
// Kernel 2: fp16 MFMA flash attention, dual fixed-max softmax.
// (unchanged from round 6: staging verified coalesced, 0 conflicts)
// ---------------------------------------------------------------------------
__global__ __launch_bounds__(256, 3)
void attn_kernel(const unsigned short* __restrict__ QG, const unsigned short* __restrict__ KG,
                 const unsigned short* __restrict__ VG,
                 unsigned short* __restrict__ ObR, unsigned short* __restrict__ ObI) {
    __shared__ unsigned short Ks[2][2048];     // [r,i][32 k][64 d] swizzled
    __shared__ unsigned short Vt[2][2560];     // [r,i][64 d][40(32 k)] padded
    __shared__ unsigned short Ps[2][4][640];   // [r,i][wave][16 q][40(32 k)] padded

    const int n   = blockIdx.x;
    const int bh  = (n & 7) * 4 + (n >> 7);    // XCD-local bh group
    const int q0  = ((n >> 3) & 15) * 64;
    const int b   = bh >> 3;
    const int h   = bh & 7;

    const int tid  = threadIdx.x;
    const int w    = tid >> 6;
    const int lane = tid & 63;
    const int quad = lane >> 4;
    const int l15  = lane & 15;

    half8 qr[2], qi[2], qmi[2];
    #pragma unroll
    for (int kc = 0; kc < 2; ++kc) {
        size_t qb = ((size_t)bh * SS + q0 + w * 16 + l15) * DHD + kc * 32 + quad * 8;
        qr[kc]  = *(const half8*)(QG + 0 * PL + qb);
        qi[kc]  = *(const half8*)(QG + 1 * PL + qb);
        qmi[kc] = negh(qi[kc]);
    }

    f32x4 Arr[4], Ari[4], Air[4], Aii[4];
    #pragma unroll
    for (int i = 0; i < 4; ++i) { Arr[i] = (f32x4)0.f; Ari[i] = (f32x4)0.f; Air[i] = (f32x4)0.f; Aii[i] = (f32x4)0.f; }
    float lrp[4] = {0.f, 0.f, 0.f, 0.f}, lip[4] = {0.f, 0.f, 0.f, 0.f};

    unsigned short* PrW = Ps[0][w];
    unsigned short* PiW = Ps[1][w];

    const int kr = tid >> 3, sg = (tid & 7) * 8;   // K: [32k][64d]
    const int dv = tid >> 2, sv = (tid & 3) * 8;   // V: [64d][32k]

    for (int kt = 0; kt < SS; kt += 32) {
        if (kt) __syncthreads();
        #pragma unroll
        for (int p = 0; p < 2; ++p) {
            *(uint4*)&Ks[p][kr * 64 + (sg ^ ((kr & 7) << 3))] =
                *(const uint4*)(KG + (size_t)p * PL + ((size_t)bh * SS + kt + kr) * DHD + sg);
            *(uint4*)&Vt[p][dv * 40 + sv] =
                *(const uint4*)(VG + (size_t)p * PL + ((size_t)bh * DHD + dv) * SS + kt + sv);
        }
        __syncthreads();

        f32x4 Sr[2], Si[2];
        Sr[0] = (f32x4)0.f; Sr[1] = (f32x4)0.f; Si[0] = (f32x4)0.f; Si[1] = (f32x4)0.f;
        #pragma unroll
        for (int kc = 0; kc < 2; ++kc) {
            const int dl = kc * 32 + quad * 8;
            #pragma unroll
            for (int nt = 0; nt < 2; ++nt) {
                const int krow = nt * 16 + l15;
                half8 krF = ldh64(Ks[0], krow, dl);
                half8 kiF = ldh64(Ks[1], krow, dl);
                MFMA16(Sr[nt], qr[kc],  krF);   // Sr = QrKr - QiKi
                MFMA16(Sr[nt], qmi[kc], kiF);
                MFMA16(Si[nt], qr[kc],  kiF);   // Si = QrKi + QiKr
                MFMA16(Si[nt], qi[kc],  krF);
            }
        }

        #pragma unroll
        for (int nt = 0; nt < 2; ++nt) {
            #pragma unroll
            for (int reg = 0; reg < 4; ++reg) {
                union { _Float16 h; unsigned short u; } cr, ci;
                cr.h = (_Float16)__expf(Sr[nt][reg] * 0.125f);
                ci.h = (_Float16)__expf(Si[nt][reg] * 0.125f);
                lrp[reg] += (float)cr.h;       // l from rounded p: consistent weights
                lip[reg] += (float)ci.h;
                int qq = quad * 4 + reg;
                int kcol = nt * 16 + l15;
                PrW[qq * 40 + kcol] = cr.u;
                PiW[qq * 40 + kcol] = ci.u;
            }
        }
        // wave-private LDS round-trip; compiler inserts lgkmcnt, no barrier

        {
            const int kl = quad * 8;
            half8 prF = ldh40(PrW, l15, kl);
            half8 piF = ldh40(PiW, l15, kl);
            #pragma unroll
            for (int dt = 0; dt < 4; ++dt) {
                const int d = dt * 16 + l15;
                half8 vrF = ldh40(Vt[0], d, kl);
                half8 viF = ldh40(Vt[1], d, kl);
                MFMA16(Arr[dt], prF, vrF);
                MFMA16(Ari[dt], prF, viF);
                MFMA16(Air[dt], piF, vrF);
                MFMA16(Aii[dt], piF, viF);
            }
        }
    }

    float ir[4], ii[4];
    #pragma unroll
    for (int reg = 0; reg < 4; ++reg) {
        float a = lrp[reg], c = lip[reg];
        #pragma unroll
        for (int mk = 1; mk < 16; mk <<= 1) {
            a += __shfl_xor(a, mk);
            c += __shfl_xor(c, mk);
        }
        ir[reg] = 1.f / a;
        ii[reg] = 1.f / c;
    }
    #pragma unroll
    for (int dt = 0; dt < 4; ++dt) {
        #pragma unroll
        for (int reg = 0; reg < 4; ++reg) {
            int q   = q0 + w * 16 + quad * 4 + reg;
            int col = h * DHD + dt * 16 + l15;
            union { _Float16 h; unsigned short u; } cr, ci;
            cr.h = (_Float16)(Arr[dt][reg] * ir[reg] - Aii[dt][reg] * ii[reg]);
            ci.h = (_Float16)(Ari[dt][reg] * ir[reg] + Air[dt][reg] * ii[reg]);
            size_t o = ((size_t)b * SS + q) * DD + col;
            ObR[o] = cr.u;
            ObI[o] = ci.u;
        }
    }
}

// ---------------------------------------------------------------------------
// Kernel 3: residual + dual LayerNorm over D (biased var, eps inside sqrt)
// ---------------------------------------------------------------------------
__global__ __launch_bounds__(256)
void ln_kernel(const unsigned short* __restrict__ OrP, const unsigned short* __restrict__ OiP,
               const float2* __restrict__ Qin,
               const float* __restrict__ gr, const float* __restrict__ br,
               const float* __restrict__ gi, const float* __restrict__ bi,
               float2* __restrict__ out) {
    const int row = blockIdx.x;           // b*S + s
    const int tid = threadIdx.x;
    const size_t base = (size_t)row * DD;
    const int e0 = 2 * tid, e1 = 2 * tid + 1;

    union { unsigned int u; _Float16 h[2]; } tr, ti;
    tr.u = *(const unsigned int*)(OrP + base + e0);
    ti.u = *(const unsigned int*)(OiP + base + e0);
    float2 r0 = Qin[base + e0];
    float2 r1 = Qin[base + e1];
    float xr0 = (float)tr.h[0] + r0.x;
    float xr1 = (float)tr.h[1] + r1.x;
    float xi0 = (float)ti.h[0] + r0.y;
    float xi1 = (float)ti.h[1] + r1.y;

    float sr = xr0 + xr1;
    float si = xi0 + xi1;
    float qr = xr0 * xr0 + xr1 * xr1;
    float qi = xi0 * xi0 + xi1 * xi1;
    #pragma unroll
    for (int off = 32; off > 0; off >>= 1) {
        sr += __shfl_down(sr, off);
        si += __shfl_down(si, off);
        qr += __shfl_down(qr, off);
        qi += __shfl_down(qi, off);
    }
    __shared__ float red[4][4];
    __shared__ float stat[4];
    int lane = tid & 63, wid = tid >> 6;
    if (lane == 0) { red[wid][0] = sr; red[wid][1] = si; red[wid][2] = qr; red[wid][3] = qi; }
    __syncthreads();
    if (tid == 0) {
        sr = red[0][0] + red[1][0] + red[2][0] + red[3][0];
        si = red[0][1] + red[1][1] + red[2][1] + red[3][1];
        qr = red[0][2] + red[1][2] + red[2][2] + red[3][2];
        qi = red[0][3] + red[1][3] + red[2][3] + red[3][3];
        float mur = sr * (1.f / DD), mui = si * (1.f / DD);
        float vr = qr * (1.f / DD) - mur * mur;
        float vi = qi * (1.f / DD) - mui * mui;
        stat[0] = mur; stat[1] = mui;
        stat[2] = rsqrtf(vr + LN_EPS); stat[3] = rsqrtf(vi + LN_EPS);
    }
    __syncthreads();
    float mur = stat[0], mui = stat[1], rsr = stat[2], rsi = stat[3];
    out[base + e0] = make_float2((xr0 - mur) * rsr * gr[e0] + br[e0],
                                 (xi0 - mui) * rsi * gi[e0] + bi[e0]);
    out[base + e1] = make_float2((xr1 - mur) * rsr * gr[e1] + br[e1],
                                 (xi1 - mui) * rsi * gi[e1] + bi[e1]);
}

// ---------------------------------------------------------------------------
extern "C" void kernel_launch(void* const* d_in, const int* in_sizes, int n_in,
                              void* d_out, int out_size, void* d_ws, size_t ws_size,
                              hipStream_t stream) {
    const float2* q  = (const float2*)d_in[0];
    const float2* k  = (const float2*)d_in[1];
    const float2* v  = (const float2*)d_in[2];
    const float2* Wq = (const float2*)d_in[3];
    const float2* bq = (const float2*)d_in[4];
    const float2* Wk = (const float2*)d_in[5];
    const float2* bk = (const float2*)d_in[6];
    const float2* Wv = (const float2*)d_in[7];
    const float2* bv = (const float2*)d_in[8];
    const float*  gr = (const float*)d_in[9];
    const float*  br = (const float*)d_in[10];
    const float*  gi = (const float*)d_in[11];
    const float*  bi = (const float*)d_in[12];

    // workspace (fp16 elements): X planes, W planes, Q/K/V planes, Ob planes
    unsigned short* XP  = (unsigned short*)d_ws;           // 3*2*PL  [q|k|v][r,i][BS*D]
    unsigned short* WP  = XP + (size_t)6 * PL;             // 3*2*WPL
    unsigned short* QG  = WP + (size_t)6 * WPL;            // 2*PL  [BH][S][64]
    unsigned short* KG  = QG + (size_t)2 * PL;             // 2*PL  [BH][S][64]
    unsigned short* VG  = KG + (size_t)2 * PL;             // 2*PL  [BH][64][S] (transposed)
    unsigned short* ObR = VG + (size_t)2 * PL;             // PL
    unsigned short* ObI = ObR + (size_t)PL;                // PL  (~62 MB total)

    cvt_kernel<<<dim3(4096, 3), 256, 0, stream>>>(q, k, v, XP, PL);
    cvt_kernel<<<dim3(512, 3), 256, 0, stream>>>(Wq, Wk, Wv, WP, WPL);
    proj_kernel<<<dim3(64, 8, 3), 256, 0, stream>>>(XP, WP, bq, bk, bv, QG, KG, VG);
    attn_kernel<<<dim3(512), 256, 0, stream>>>(QG, KG, VG, ObR, ObI);
    ln_kernel<<<dim3(BB * SS), 256, 0, stream>>>(ObR, ObI, q, gr, br, gi, bi, (float2*)d_out);
}

// Round 8
// 224.729 us; speedup vs baseline: 1.9587x; 1.0040x over previous
//
#include <hip/hip_runtime.h>
#include <math.h>

#define BB  4
#define SS  1024
#define DD  512
#define HH  8
#define DHD 64
#define PL  2097152      // elements per Q/K/V/Ob plane (also B*S*D)
#define WPL 262144       // elements per W plane

constexpr float LN_EPS = 1e-5f;

using half4 = __attribute__((ext_vector_type(4))) _Float16;
using half8 = __attribute__((ext_vector_type(8))) _Float16;
using f32x4 = __attribute__((ext_vector_type(4))) float;

__device__ __forceinline__ half8 negh(half8 a) {
    union { half8 h; unsigned int u[4]; } t;
    t.h = a;
    #pragma unroll
    for (int i = 0; i < 4; ++i) t.u[i] ^= 0x80008000u;
    return t.h;
}
// 64-wide swizzled rows (XOR (row&7)<<3, 8-half granules): conflict-free b128
__device__ __forceinline__ half8 ldh64(const unsigned short* p, int row, int col) {
    return *(const half8*)(p + row * 64 + (col ^ ((row & 7) << 3)));
}
#define MFMA16(acc, a, b) acc = __builtin_amdgcn_mfma_f32_16x16x32_f16(a, b, acc, 0, 0, 0)

// ---------------------------------------------------------------------------
// Kernel 0: fp32 complex -> fp16 r/i planes (used for q/k/v inputs and W).
// ---------------------------------------------------------------------------
__global__ __launch_bounds__(256)
void cvt_kernel(const float2* __restrict__ s0, const float2* __restrict__ s1,
                const float2* __restrict__ s2, unsigned short* __restrict__ dst,
                int planeElems) {
    const int z = blockIdx.y;
    const float2* src = z == 0 ? s0 : (z == 1 ? s1 : s2);
    unsigned short* base = dst + (size_t)z * 2 * planeElems;
    const int idx = (blockIdx.x * 256 + threadIdx.x) * 2;   // complex index
    float4 t = *(const float4*)(src + idx);
    union { _Float16 h[2]; unsigned int u; } r, i;
    r.h[0] = (_Float16)t.x; r.h[1] = (_Float16)t.z;
    i.h[0] = (_Float16)t.y; i.h[1] = (_Float16)t.w;
    ((unsigned int*)(base))[idx >> 1] = r.u;
    ((unsigned int*)(base + planeElems))[idx >> 1] = i.u;
}

// ---------------------------------------------------------------------------
// Kernel 1: complex projection, single-fp16 MFMA (unchanged from round 7).
// ---------------------------------------------------------------------------
__global__ __launch_bounds__(256, 5)
void proj_kernel(const unsigned short* __restrict__ XP,
                 const unsigned short* __restrict__ WP,
                 const float2* __restrict__ bq, const float2* __restrict__ bk,
                 const float2* __restrict__ bv,
                 unsigned short* __restrict__ QG, unsigned short* __restrict__ KG,
                 unsigned short* __restrict__ VG) {
    const unsigned short* XR = XP + (size_t)blockIdx.z * 2 * PL;
    const unsigned short* XI = XR + PL;
    const unsigned short* WR = WP + (size_t)blockIdx.z * 2 * WPL;
    const unsigned short* WI = WR + WPL;
    const float2* bias; unsigned short* outP;
    if (blockIdx.z == 0)      { bias = bq; outP = QG; }
    else if (blockIdx.z == 1) { bias = bk; outP = KG; }
    else                      { bias = bv; outP = VG; }
    const bool isV = (blockIdx.z == 2);

    __shared__ unsigned short Xs[2][4096];   // [r,i][64 m][64 d] swizzled
    __shared__ unsigned short Ws[2][4096];   // [r,i][64 e][64 d] swizzled

    const int tid  = threadIdx.x;
    const int w    = tid >> 6;
    const int lane = tid & 63;
    const int quad = lane >> 4;
    const int l15  = lane & 15;
    const int m0   = blockIdx.x * 64;
    const int h    = blockIdx.y;
    const int e0   = h * 64;

    const int r8 = tid >> 3;        // 0..31 (staging row base)
    const int g8 = tid & 7;         // granule 0..7 (8 halfs)

    f32x4 Sr[4], Si[4];
    #pragma unroll
    for (int i = 0; i < 4; ++i) { Sr[i] = (f32x4)0.f; Si[i] = (f32x4)0.f; }

    for (int dc = 0; dc < DD; dc += 64) {
        if (dc) __syncthreads();
        #pragma unroll
        for (int it = 0; it < 2; ++it) {
            const int row = it * 32 + r8;
            const int off = row * 64 + ((g8 ^ (row & 7)) << 3);
            const size_t xo = (size_t)(m0 + row) * DD + dc + g8 * 8;
            const size_t wo = (size_t)(e0 + row) * DD + dc + g8 * 8;
            *(uint4*)&Xs[0][off] = *(const uint4*)(XR + xo);
            *(uint4*)&Xs[1][off] = *(const uint4*)(XI + xo);
            *(uint4*)&Ws[0][off] = *(const uint4*)(WR + wo);
            *(uint4*)&Ws[1][off] = *(const uint4*)(WI + wo);
        }
        __syncthreads();

        const int mrow = w * 16 + l15;
        #pragma unroll
        for (int kc = 0; kc < 2; ++kc) {
            const int dl = kc * 32 + quad * 8;
            half8 xr  = ldh64(Xs[0], mrow, dl);
            half8 xi  = ldh64(Xs[1], mrow, dl);
            half8 xmi = negh(xi);
            #pragma unroll
            for (int et = 0; et < 4; ++et) {
                const int er = et * 16 + l15;
                half8 wr = ldh64(Ws[0], er, dl);
                half8 wi = ldh64(Ws[1], er, dl);
                MFMA16(Sr[et], xr,  wr);   // Sr = XrWr - XiWi
                MFMA16(Sr[et], xmi, wi);
                MFMA16(Si[et], xr,  wi);   // Si = XrWi + XiWr
                MFMA16(Si[et], xi,  wr);
            }
        }
    }

    // epilogue: + bias, fp16, write planes (V transposed)
    #pragma unroll
    for (int et = 0; et < 4; ++et) {
        const int col = et * 16 + l15;
        float2 bb = bias[e0 + col];
        #pragma unroll
        for (int reg = 0; reg < 4; ++reg) {
            int m = m0 + w * 16 + quad * 4 + reg;
            int b = m >> 10;
            int s = m & 1023;
            int bh = b * HH + h;
            union { _Float16 h; unsigned short u; } cr, ci;
            cr.h = (_Float16)(Sr[et][reg] + bb.x);
            ci.h = (_Float16)(Si[et][reg] + bb.y);
            size_t o = isV ? ((size_t)bh * DHD + col) * SS + s
                           : ((size_t)bh * SS + s) * DHD + col;
            outP[0 * PL + o] = cr.u;
            outP[1 * PL + o] = ci.u;
        }
    }
}

// ---------------------------------------------------------------------------
// Kernel 2: fp16 MFMA flash attention, S^T formulation.
// Block: 4 waves, q-tile 64, k-tile 64/iter. Waves split 2x2:
//   scores: (sw = q-half, tw = k-half): S^T = K(A, from LDS) x Q(B, registers)
//           -> C-layout has fixed q per lane, 4-consecutive-k per reg group
//           -> P written as packed b64 into q-major P[q][k].
//   PV:     (sw = q-half, tw = d-half): A = P[q][k] b128, B = V^T[d][k] b128.
// Width-72 LDS rows: stride 36 dw = 4 mod 32 -> all accesses <=2-way (free).
// K/V fragment duplication drops 4x -> 2x; P traffic 128 b16 -> 32 b64.
// ---------------------------------------------------------------------------
#define AWID 72
__global__ __launch_bounds__(256, 2)
void attn_kernel(const unsigned short* __restrict__ QG, const unsigned short* __restrict__ KG,
                 const unsigned short* __restrict__ VG,
                 unsigned short* __restrict__ ObR, unsigned short* __restrict__ ObI) {
    __shared__ unsigned short Ks[2][64 * AWID];   // [r,i][k][d]
    __shared__ unsigned short Vt[2][64 * AWID];   // [r,i][d][k]
    __shared__ unsigned short Ps[2][64 * AWID];   // [r,i][q][k]
    __shared__ float lbuf[2][2][64];              // [plane][k-half][q]

    const int n   = blockIdx.x;
    const int bh  = (n & 7) * 4 + (n >> 7);       // XCD-local bh group
    const int q0  = ((n >> 3) & 15) * 64;
    const int b   = bh >> 3;
    const int h   = bh & 7;

    const int tid  = threadIdx.x;
    const int w    = tid >> 6;
    const int lane = tid & 63;
    const int quad = lane >> 4;
    const int l15  = lane & 15;
    const int sw   = w & 1;        // q-half (both phases)
    const int tw   = w >> 1;       // k-half (scores) / d-half (PV)

    // Q in B-layout registers: lane = q col, quad*8+j = d within 32-window
    half8 qfr[2][2], qfi[2][2], qfmi[2][2];       // [qt][kc]
    #pragma unroll
    for (int qt = 0; qt < 2; ++qt)
        #pragma unroll
        for (int kc = 0; kc < 2; ++kc) {
            size_t qa = ((size_t)bh * SS + q0 + sw * 32 + qt * 16 + l15) * DHD + kc * 32 + quad * 8;
            qfr[qt][kc]  = *(const half8*)(QG + qa);
            qfi[qt][kc]  = *(const half8*)(QG + PL + qa);
            qfmi[qt][kc] = negh(qfi[qt][kc]);
        }

    f32x4 acc[2][2][4];            // [qt][dt][PrVr,PrVi,PiVr,PiVi]
    #pragma unroll
    for (int qt = 0; qt < 2; ++qt)
        #pragma unroll
        for (int dt = 0; dt < 2; ++dt)
            #pragma unroll
            for (int p = 0; p < 4; ++p) acc[qt][dt][p] = (f32x4)0.f;
    float lacc[2][2] = {{0.f, 0.f}, {0.f, 0.f}};  // [qt][plane]

    const int srow = tid >> 3;      // 0..31
    const int sg   = (tid & 7) * 8; // granule col

    for (int kt = 0; kt < SS; kt += 64) {
        __syncthreads();
        // ---- stage K [64k][64d] and V^T [64d][64k] (one row per 8 lanes) ----
        #pragma unroll
        for (int p = 0; p < 2; ++p)
            #pragma unroll
            for (int it = 0; it < 2; ++it) {
                const int r = it * 32 + srow;
                *(uint4*)&Ks[p][r * AWID + sg] =
                    *(const uint4*)(KG + (size_t)p * PL + ((size_t)bh * SS + kt + r) * DHD + sg);
                *(uint4*)&Vt[p][r * AWID + sg] =
                    *(const uint4*)(VG + (size_t)p * PL + ((size_t)bh * DHD + r) * SS + kt + sg);
            }
        __syncthreads();

        // ---- scores: S^T[k32][q32] for this wave's (tw k-half, sw q-half) ----
        f32x4 Sr[2][2], Si[2][2];   // [kt2][qt]
        #pragma unroll
        for (int a = 0; a < 2; ++a)
            #pragma unroll
            for (int c = 0; c < 2; ++c) { Sr[a][c] = (f32x4)0.f; Si[a][c] = (f32x4)0.f; }
        #pragma unroll
        for (int kc = 0; kc < 2; ++kc) {
            #pragma unroll
            for (int kt2 = 0; kt2 < 2; ++kt2) {
                const int krow = tw * 32 + kt2 * 16 + l15;
                half8 akr = *(const half8*)&Ks[0][krow * AWID + kc * 32 + quad * 8];
                half8 aki = *(const half8*)&Ks[1][krow * AWID + kc * 32 + quad * 8];
                #pragma unroll
                for (int qt = 0; qt < 2; ++qt) {
                    MFMA16(Sr[kt2][qt], akr, qfr[qt][kc]);    // K_r . Q_r
                    MFMA16(Sr[kt2][qt], aki, qfmi[qt][kc]);   // -K_i . Q_i
                    MFMA16(Si[kt2][qt], aki, qfr[qt][kc]);    // K_i . Q_r
                    MFMA16(Si[kt2][qt], akr, qfi[qt][kc]);    // K_r . Q_i
                }
            }
        }

        // ---- exp -> P (b64 packed, q-major), l partial per lane ----
        #pragma unroll
        for (int kt2 = 0; kt2 < 2; ++kt2)
            #pragma unroll
            for (int qt = 0; qt < 2; ++qt) {
                half4 pr, pi;
                float sr_ = 0.f, si_ = 0.f;
                #pragma unroll
                for (int reg = 0; reg < 4; ++reg) {
                    float er = __expf(Sr[kt2][qt][reg] * 0.125f);
                    float ei = __expf(Si[kt2][qt][reg] * 0.125f);
                    pr[reg] = (_Float16)er;
                    pi[reg] = (_Float16)ei;
                    sr_ += (float)pr[reg];   // l from rounded p: consistent weights
                    si_ += (float)pi[reg];
                }
                lacc[qt][0] += sr_;
                lacc[qt][1] += si_;
                const int qrow = sw * 32 + qt * 16 + l15;
                const int kcol = tw * 32 + kt2 * 16 + quad * 4;
                *(half4*)&Ps[0][qrow * AWID + kcol] = pr;
                *(half4*)&Ps[1][qrow * AWID + kcol] = pi;
            }
        __syncthreads();

        // ---- PV: out tile q32 (sw) x d32 (tw), k64 accumulation ----
        #pragma unroll
        for (int kc = 0; kc < 2; ++kc) {
            half8 ap[2][2];   // [qt][plane]
            #pragma unroll
            for (int qt = 0; qt < 2; ++qt) {
                const int qrow = sw * 32 + qt * 16 + l15;
                ap[qt][0] = *(const half8*)&Ps[0][qrow * AWID + kc * 32 + quad * 8];
                ap[qt][1] = *(const half8*)&Ps[1][qrow * AWID + kc * 32 + quad * 8];
            }
            #pragma unroll
            for (int dt = 0; dt < 2; ++dt) {
                const int drow = tw * 32 + dt * 16 + l15;
                half8 bvr = *(const half8*)&Vt[0][drow * AWID + kc * 32 + quad * 8];
                half8 bvi = *(const half8*)&Vt[1][drow * AWID + kc * 32 + quad * 8];
                #pragma unroll
                for (int qt = 0; qt < 2; ++qt) {
                    MFMA16(acc[qt][dt][0], ap[qt][0], bvr);
                    MFMA16(acc[qt][dt][1], ap[qt][0], bvi);
                    MFMA16(acc[qt][dt][2], ap[qt][1], bvr);
                    MFMA16(acc[qt][dt][3], ap[qt][1], bvi);
                }
            }
        }
    }

    // ---- combine l: quad-reduce (lane's k-subset -> full k-half), store ----
    __syncthreads();
    #pragma unroll
    for (int qt = 0; qt < 2; ++qt)
        #pragma unroll
        for (int p = 0; p < 2; ++p) {
            float v = lacc[qt][p];
            v += __shfl_xor(v, 16);
            v += __shfl_xor(v, 32);
            if (lane < 16) lbuf[p][tw][sw * 32 + qt * 16 + lane] = v;
        }
    __syncthreads();

    // ---- epilogue: normalize, combine complex, store fp16 planes ----
    #pragma unroll
    for (int qt = 0; qt < 2; ++qt)
        #pragma unroll
        for (int reg = 0; reg < 4; ++reg) {
            const int qloc = sw * 32 + qt * 16 + quad * 4 + reg;
            const float ir = 1.f / (lbuf[0][0][qloc] + lbuf[0][1][qloc]);
            const float ii = 1.f / (lbuf[1][0][qloc] + lbuf[1][1][qloc]);
            #pragma unroll
            for (int dt = 0; dt < 2; ++dt) {
                const int d = tw * 32 + dt * 16 + l15;
                union { _Float16 h; unsigned short u; } cr, ci;
                cr.h = (_Float16)(acc[qt][dt][0][reg] * ir - acc[qt][dt][3][reg] * ii);
                ci.h = (_Float16)(acc[qt][dt][1][reg] * ir + acc[qt][dt][2][reg] * ii);
                size_t o = ((size_t)b * SS + q0 + qloc) * DD + h * DHD + d;
                ObR[o] = cr.u;
                ObI[o] = ci.u;
            }
        }
}

// ---------------------------------------------------------------------------
// Kernel 3: residual + dual LayerNorm over D (biased var, eps inside sqrt)
// ---------------------------------------------------------------------------
__global__ __launch_bounds__(256)
void ln_kernel(const unsigned short* __restrict__ OrP, const unsigned short* __restrict__ OiP,
               const float2* __restrict__ Qin,
               const float* __restrict__ gr, const float* __restrict__ br,
               const float* __restrict__ gi, const float* __restrict__ bi,
               float2* __restrict__ out) {
    const int row = blockIdx.x;           // b*S + s
    const int tid = threadIdx.x;
    const size_t base = (size_t)row * DD;
    const int e0 = 2 * tid, e1 = 2 * tid + 1;

    union { unsigned int u; _Float16 h[2]; } tr, ti;
    tr.u = *(const unsigned int*)(OrP + base + e0);
    ti.u = *(const unsigned int*)(OiP + base + e0);
    float2 r0 = Qin[base + e0];
    float2 r1 = Qin[base + e1];
    float xr0 = (float)tr.h[0] + r0.x;
    float xr1 = (float)tr.h[1] + r1.x;
    float xi0 = (float)ti.h[0] + r0.y;
    float xi1 = (float)ti.h[1] + r1.y;

    float sr = xr0 + xr1;
    float si = xi0 + xi1;
    float qr = xr0 * xr0 + xr1 * xr1;
    float qi = xi0 * xi0 + xi1 * xi1;
    #pragma unroll
    for (int off = 32; off > 0; off >>= 1) {
        sr += __shfl_down(sr, off);
        si += __shfl_down(si, off);
        qr += __shfl_down(qr, off);
        qi += __shfl_down(qi, off);
    }
    __shared__ float red[4][4];
    __shared__ float stat[4];
    int lane = tid & 63, wid = tid >> 6;
    if (lane == 0) { red[wid][0] = sr; red[wid][1] = si; red[wid][2] = qr; red[wid][3] = qi; }
    __syncthreads();
    if (tid == 0) {
        sr = red[0][0] + red[1][0] + red[2][0] + red[3][0];
        si = red[0][1] + red[1][1] + red[2][1] + red[3][1];
        qr = red[0][2] + red[1][2] + red[2][2] + red[3][2];
        qi = red[0][3] + red[1][3] + red[2][3] + red[3][3];
        float mur = sr * (1.f / DD), mui = si * (1.f / DD);
        float vr = qr * (1.f / DD) - mur * mur;
        float vi = qi * (1.f / DD) - mui * mui;
        stat[0] = mur; stat[1] = mui;
        stat[2] = rsqrtf(vr + LN_EPS); stat[3] = rsqrtf(vi + LN_EPS);
    }
    __syncthreads();
    float mur = stat[0], mui = stat[1], rsr = stat[2], rsi = stat[3];
    out[base + e0] = make_float2((xr0 - mur) * rsr * gr[e0] + br[e0],
                                 (xi0 - mui) * rsi * gi[e0] + bi[e0]);
    out[base + e1] = make_float2((xr1 - mur) * rsr * gr[e1] + br[e1],
                                 (xi1 - mui) * rsi * gi[e1] + bi[e1]);
}

// ---------------------------------------------------------------------------
extern "C" void kernel_launch(void* const* d_in, const int* in_sizes, int n_in,
                              void* d_out, int out_size, void* d_ws, size_t ws_size,
                              hipStream_t stream) {
    const float2* q  = (const float2*)d_in[0];
    const float2* k  = (const float2*)d_in[1];
    const float2* v  = (const float2*)d_in[2];
    const float2* Wq = (const float2*)d_in[3];
    const float2* bq = (const float2*)d_in[4];
    const float2* Wk = (const float2*)d_in[5];
    const float2* bk = (const float2*)d_in[6];
    const float2* Wv = (const float2*)d_in[7];
    const float2* bv = (const float2*)d_in[8];
    const float*  gr = (const float*)d_in[9];
    const float*  br = (const float*)d_in[10];
    const float*  gi = (const float*)d_in[11];
    const float*  bi = (const float*)d_in[12];

    // workspace (fp16 elements): X planes, W planes, Q/K/V planes, Ob planes
    unsigned short* XP  = (unsigned short*)d_ws;           // 3*2*PL
    unsigned short* WP  = XP + (size_t)6 * PL;             // 3*2*WPL
    unsigned short* QG  = WP + (size_t)6 * WPL;            // 2*PL  [BH][S][64]
    unsigned short* KG  = QG + (size_t)2 * PL;             // 2*PL  [BH][S][64]
    unsigned short* VG  = KG + (size_t)2 * PL;             // 2*PL  [BH][64][S] (transposed)
    unsigned short* ObR = VG + (size_t)2 * PL;             // PL
    unsigned short* ObI = ObR + (size_t)PL;                // PL

    cvt_kernel<<<dim3(4096, 3), 256, 0, stream>>>(q, k, v, XP, PL);
    cvt_kernel<<<dim3(512, 3), 256, 0, stream>>>(Wq, Wk, Wv, WP, WPL);
    proj_kernel<<<dim3(64, 8, 3), 256, 0, stream>>>(XP, WP, bq, bk, bv, QG, KG, VG);
    attn_kernel<<<dim3(512), 256, 0, stream>>>(QG, KG, VG, ObR, ObI);
    ln_kernel<<<dim3(BB * SS), 256, 0, stream>>>(ObR, ObI, q, gr, br, gi, bi, (float2*)d_out);
}